// Round 7
// baseline (549.221 us; speedup 1.0000x reference)
//
#include <hip/hip_runtime.h>
#include <math.h>

#define N_NODES 100000
#define N_EDGES 600000
#define N_GRAPHS 512
#define D 128
#define SCAN_BS 1024
#define SCAN_NBC ((N_NODES + SCAN_BS - 1) / SCAN_BS)   // 98
#define NPART 8
#define PART_SZ (N_NODES / NPART)                      // 12500
#define E4 (N_EDGES / 4)                               // 150000
#define SPLIT_B 12500                                  // (N*D/4)/256

typedef unsigned short u16;
typedef __attribute__((ext_vector_type(8))) short short8;
typedef __attribute__((ext_vector_type(4))) float f32x4;

__device__ __forceinline__ u16 f2bf(float f) {
    unsigned int u = __float_as_uint(f);
    u += 0x7FFFu + ((u >> 16) & 1u);
    return (u16)(u >> 16);
}
__device__ __forceinline__ float bf2f(u16 h) {
    return __uint_as_float(((unsigned int)h) << 16);
}
// fp32 -> (hi bf16 bits, lo bf16 bits) in low 16 of each
__device__ __forceinline__ void split2(float f, unsigned int& h16, unsigned int& l16) {
    unsigned int u = __float_as_uint(f);
    unsigned int hb = (u + (0x7FFFu + ((u >> 16) & 1u))) & 0xffff0000u;
    float lo = f - __uint_as_float(hb);
    unsigned int ul = __float_as_uint(lo);
    h16 = hb >> 16;
    l16 = (ul + (0x7FFFu + ((ul >> 16) & 1u))) >> 16;
}

// async global->LDS, 16 B per lane. LDS dest must be wave-uniform base + lane*16.
typedef __attribute__((address_space(1))) const unsigned int gas_u32;
typedef __attribute__((address_space(3))) unsigned int las_u32;
__device__ __forceinline__ void gload16(const void* g, void* l) {
    __builtin_amdgcn_global_load_lds((gas_u32*)g, (las_u32*)l, 16, 0, 0);
}

// ---------------- zero helper ----------------
__global__ __launch_bounds__(256) void zero_i_kernel(int* __restrict__ p, int n) {
    int i = blockIdx.x * 256 + threadIdx.x;
    if (i < n) p[i] = 0;
}

// ---------------- CSR build ----------------
// hist: plain unpartitioned (atomics execute at the device coherence point --
// R3 post-mortem). fill: KEEPS dst-range partitioning: its win is the csr_src
// SCATTER-STORE locality in the owning XCD's L2 (R2->R3).
__global__ __launch_bounds__(256) void hist_kernel(const int* __restrict__ dst,
                                                   int* __restrict__ deg) {
    int e = blockIdx.x * 256 + threadIdx.x;
    if (e < N_EDGES) atomicAdd(&deg[dst[e]], 1);
}

__global__ __launch_bounds__(1024) void scan1_kernel(const int* __restrict__ deg,
                                                     int* __restrict__ excl,
                                                     int* __restrict__ blocksum) {
    __shared__ int buf[2][SCAN_BS];
    const int t = threadIdx.x;
    const int gid = blockIdx.x * SCAN_BS + t;
    int v = (gid < N_NODES) ? deg[gid] : 0;
    buf[0][t] = v;
    __syncthreads();
    int pi = 0;
    for (int off = 1; off < SCAN_BS; off <<= 1) {
        int val = buf[pi][t];
        if (t >= off) val += buf[pi][t - off];
        buf[pi ^ 1][t] = val;
        pi ^= 1;
        __syncthreads();
    }
    int incl = buf[pi][t];
    if (gid < N_NODES) excl[gid] = incl - v;
    if (t == SCAN_BS - 1) blocksum[blockIdx.x] = incl;
}

// scan3 with the block-total prefix computed locally (merged scan2)
__global__ __launch_bounds__(256) void scan3_kernel(const int* __restrict__ excl,
                                                    const int* __restrict__ blocksum,
                                                    int* __restrict__ rowptr) {
    __shared__ int buf[2][128];
    const int t = threadIdx.x;
    if (t < 128) buf[0][t] = (t < SCAN_NBC) ? blocksum[t] : 0;
    __syncthreads();
    int pi = 0;
    for (int off = 1; off < 128; off <<= 1) {
        if (t < 128) {
            int val = buf[pi][t];
            if (t >= off) val += buf[pi][t - off];
            buf[pi ^ 1][t] = val;
        }
        pi ^= 1;
        __syncthreads();
    }
    const int i = blockIdx.x * 256 + t;
    if (i < N_NODES) {
        const int j = i / SCAN_BS;
        const int pref = (j == 0) ? 0 : buf[pi][j - 1];
        rowptr[i] = excl[i] + pref;
    }
    if (i == 0) rowptr[N_NODES] = N_EDGES;
}

__global__ __launch_bounds__(256) void fill_kernel(const int* __restrict__ src,
                                                   const int* __restrict__ dst,
                                                   const int* __restrict__ rowptr,
                                                   int* __restrict__ fill,
                                                   int* __restrict__ csr_src) {
    const int lo = (blockIdx.x & (NPART - 1)) * PART_SZ;
    const int i4 = (blockIdx.x >> 3) * 256 + threadIdx.x;
    if (i4 >= E4) return;
    const int4 d4 = ((const int4*)dst)[i4];
    const int4 s4 = ((const int4*)src)[i4];
    if ((unsigned)(d4.x - lo) < (unsigned)PART_SZ) {
        int pos = rowptr[d4.x] + atomicAdd(&fill[d4.x], 1);
        csr_src[pos] = s4.x;
    }
    if ((unsigned)(d4.y - lo) < (unsigned)PART_SZ) {
        int pos = rowptr[d4.y] + atomicAdd(&fill[d4.y], 1);
        csr_src[pos] = s4.y;
    }
    if ((unsigned)(d4.z - lo) < (unsigned)PART_SZ) {
        int pos = rowptr[d4.z] + atomicAdd(&fill[d4.z], 1);
        csr_src[pos] = s4.z;
    }
    if ((unsigned)(d4.w - lo) < (unsigned)PART_SZ) {
        int pos = rowptr[d4.w] + atomicAdd(&fill[d4.w], 1);
        csr_src[pos] = s4.w;
    }
}

// ---------------- fused prep: split x into bf16 hi/lo planes + pack W ----------------
__global__ __launch_bounds__(256) void prep_kernel(const float* __restrict__ x,
                                                   u16* __restrict__ Hhi,
                                                   u16* __restrict__ Hlo,
                                                   const float* __restrict__ Wl1, const float* __restrict__ Wr1,
                                                   const float* __restrict__ Wl2, const float* __restrict__ Wr2,
                                                   const float* __restrict__ Wl3, const float* __restrict__ Wr3,
                                                   u16* __restrict__ wph, u16* __restrict__ wpl) {
    if (blockIdx.x < SPLIT_B) {
        const int i = blockIdx.x * 256 + threadIdx.x;   // 4 elems/thread
        const float4 v = ((const float4*)x)[i];
        unsigned int h0, l0, h1, l1, h2, l2, h3, l3;
        split2(v.x, h0, l0); split2(v.y, h1, l1);
        split2(v.z, h2, l2); split2(v.w, h3, l3);
        uint2 oh, ol;
        oh.x = h0 | (h1 << 16); oh.y = h2 | (h3 << 16);
        ol.x = l0 | (l1 << 16); ol.y = l2 | (l3 << 16);
        ((uint2*)Hhi)[i] = oh;
        ((uint2*)Hlo)[i] = ol;
    } else {
        const int b = (blockIdx.x - SPLIT_B) * 4 + (threadIdx.x >> 6);  // 0..191
        const int lane = threadIdx.x & 63;
        const int layer = b >> 6;
        const int t = b & 63;
        const float* Wl = (layer == 0) ? Wl1 : (layer == 1) ? Wl2 : Wl3;
        const float* Wr = (layer == 0) ? Wr1 : (layer == 1) ? Wr2 : Wr3;
        const int nt = t >> 3, kt = t & 7;
        const int n = nt * 16 + (lane & 15);
        const int k0 = kt * 32 + (lane >> 4) * 8;
        const size_t base = (size_t)layer * 32768 + (size_t)(t * 64 + lane) * 8;
        #pragma unroll
        for (int j = 0; j < 8; ++j) {
            const int k = k0 + j;
            const float w = (k < 128) ? Wl[k * 128 + n] : Wr[(k - 128) * 128 + n];
            const u16 h = f2bf(w);
            wph[base + j] = h;
            wpl[base + j] = f2bf(w - bf2f(h));
        }
    }
}

// ---------------- FUSED agg + MFMA GEMM ----------------
// h' = relu([mean_nbr(INhi) | IN] @ [Wl;Wr] + b), OUT != IN (ping-pong), so the
// neighbor gather cannot race the epilogue writes.
// R7: gather rewritten 4-neighbor-unrolled with index prefetch. R6's serial
// per-neighbor chain (4 row-loads + 1 idx-load in flight, 2 dependent round
// trips/neighbor) was latency-bound: 67 us @ 2.2 TB/s, MfmaUtil 9%. Now per
// iteration: prefetch next 4 idx (overlapped), issue 16 row-loads before
// consuming, accumulate into 2 banks (j&1) to break the fp32 add chain.
// In-flight VMEM/wave ~5 -> ~20. Root ah/al loads issued before the gather so
// their latency hides under it.
// W pipeline unchanged (R1 ledger): four 32 KB stages, 2x32 KB LDS dbuf via
// global_load_lds, raw s_barrier + counted vmcnt; gather/A loads drain before
// the first counted wait (vmcnt waits oldest-first -> stricter only).
// vmcnt(4) before C0/C1/C2, vmcnt(0) before C3. LDS 80 KB -> 2 blocks/CU.
// Layer 3: rowdot[row] = sum_col relu(.)*Wro[col] (no h' write).
__global__ __launch_bounds__(512, 4) void gemm_kernel(const u16* __restrict__ INhi,
                                                      const u16* __restrict__ INlo,
                                                      const int* __restrict__ rowptr,
                                                      const int* __restrict__ csr_src,
                                                      const u16* __restrict__ Wph,
                                                      const u16* __restrict__ Wpl,
                                                      const float* __restrict__ bias,
                                                      u16* __restrict__ OHhi,
                                                      u16* __restrict__ OHlo,
                                                      const float* __restrict__ Wro,
                                                      float* rowdot) {
    __shared__ uint4 ldsAll[5120];   // 80 KB: W dbuf [0:4096) + C bounce [4096:5120)
    const int t = threadIdx.x;
    const int lane = t & 63;
    const int wv = t >> 6;
    const int m0 = blockIdx.x * 128 + wv * 16;
    const int row16 = m0 + (lane & 15);
    int rm = row16; if (rm >= N_NODES) rm = 0;
    const int ko = (lane >> 4) * 8;

    int beg = 0, deg = 0;
    if (row16 < N_NODES) {
        beg = rowptr[row16];
        deg = rowptr[row16 + 1] - beg;
    }

    // root A fragments issued FIRST: latency hides under the gather
    short8 ah[4], al[4];
    #pragma unroll
    for (int kt = 0; kt < 4; ++kt) {
        ah[kt] = *(const short8*)(INhi + (size_t)rm * D + kt * 32 + ko);
        al[kt] = *(const short8*)(INlo + (size_t)rm * D + kt * 32 + ko);
    }

    // ---- fused aggregation: 4 neighbors in flight, 2 accumulator banks ----
    float ac[2][4][8];
    #pragma unroll
    for (int b = 0; b < 2; ++b)
        #pragma unroll
        for (int kt = 0; kt < 4; ++kt)
            #pragma unroll
            for (int j = 0; j < 8; ++j) ac[b][kt][j] = 0.f;

    int idx[4];
    #pragma unroll
    for (int j = 0; j < 4; ++j) idx[j] = (j < deg) ? csr_src[beg + j] : 0;

    for (int n = 0; __any(n < deg); n += 4) {
        int nidx[4];
        #pragma unroll
        for (int j = 0; j < 4; ++j)
            nidx[j] = (n + 4 + j < deg) ? csr_src[beg + n + 4 + j] : 0;
        #pragma unroll
        for (int j = 0; j < 4; ++j) {
            if (n + j < deg) {
                const size_t rb = (size_t)idx[j] * D + ko;
                float* a0 = ac[j & 1][0];
                float* a1 = ac[j & 1][1];
                float* a2 = ac[j & 1][2];
                float* a3 = ac[j & 1][3];
                const uint4 v0 = *(const uint4*)(INhi + rb);
                const uint4 v1 = *(const uint4*)(INhi + rb + 32);
                const uint4 v2 = *(const uint4*)(INhi + rb + 64);
                const uint4 v3 = *(const uint4*)(INhi + rb + 96);
                a0[0] += __uint_as_float(v0.x << 16); a0[1] += __uint_as_float(v0.x & 0xffff0000u);
                a0[2] += __uint_as_float(v0.y << 16); a0[3] += __uint_as_float(v0.y & 0xffff0000u);
                a0[4] += __uint_as_float(v0.z << 16); a0[5] += __uint_as_float(v0.z & 0xffff0000u);
                a0[6] += __uint_as_float(v0.w << 16); a0[7] += __uint_as_float(v0.w & 0xffff0000u);
                a1[0] += __uint_as_float(v1.x << 16); a1[1] += __uint_as_float(v1.x & 0xffff0000u);
                a1[2] += __uint_as_float(v1.y << 16); a1[3] += __uint_as_float(v1.y & 0xffff0000u);
                a1[4] += __uint_as_float(v1.z << 16); a1[5] += __uint_as_float(v1.z & 0xffff0000u);
                a1[6] += __uint_as_float(v1.w << 16); a1[7] += __uint_as_float(v1.w & 0xffff0000u);
                a2[0] += __uint_as_float(v2.x << 16); a2[1] += __uint_as_float(v2.x & 0xffff0000u);
                a2[2] += __uint_as_float(v2.y << 16); a2[3] += __uint_as_float(v2.y & 0xffff0000u);
                a2[4] += __uint_as_float(v2.z << 16); a2[5] += __uint_as_float(v2.z & 0xffff0000u);
                a2[6] += __uint_as_float(v2.w << 16); a2[7] += __uint_as_float(v2.w & 0xffff0000u);
                a3[0] += __uint_as_float(v3.x << 16); a3[1] += __uint_as_float(v3.x & 0xffff0000u);
                a3[2] += __uint_as_float(v3.y << 16); a3[3] += __uint_as_float(v3.y & 0xffff0000u);
                a3[4] += __uint_as_float(v3.z << 16); a3[5] += __uint_as_float(v3.z & 0xffff0000u);
                a3[6] += __uint_as_float(v3.w << 16); a3[7] += __uint_as_float(v3.w & 0xffff0000u);
            }
        }
        #pragma unroll
        for (int j = 0; j < 4; ++j) idx[j] = nidx[j];
    }
    const float inv = 1.0f / (float)max(deg, 1);
    short8 am[4];
    #pragma unroll
    for (int kt = 0; kt < 4; ++kt) {
        uint4 u;
        u.x = (unsigned)f2bf((ac[0][kt][0] + ac[1][kt][0]) * inv)
            | ((unsigned)f2bf((ac[0][kt][1] + ac[1][kt][1]) * inv) << 16);
        u.y = (unsigned)f2bf((ac[0][kt][2] + ac[1][kt][2]) * inv)
            | ((unsigned)f2bf((ac[0][kt][3] + ac[1][kt][3]) * inv) << 16);
        u.z = (unsigned)f2bf((ac[0][kt][4] + ac[1][kt][4]) * inv)
            | ((unsigned)f2bf((ac[0][kt][5] + ac[1][kt][5]) * inv) << 16);
        u.w = (unsigned)f2bf((ac[0][kt][6] + ac[1][kt][6]) * inv)
            | ((unsigned)f2bf((ac[0][kt][7] + ac[1][kt][7]) * inv) << 16);
        am[kt] = __builtin_bit_cast(short8, u);
    }
    __builtin_amdgcn_sched_barrier(0);   // fence gather VMEM out of the ledger

    const int cl = lane & 15;
    const int g4 = (lane >> 4) << 2;
    char* bounceB = (char*)ldsAll + 65536 + wv * 2048;   // per-wave 2 KB

    f32x4 acc8[2][4];   // [s][nt2], all indices compile-time after unroll

#define STAGE_W(Q, B) do {                                                      \
        const uint4* gh_ = (const uint4*)Wph + (Q) * 1024;                      \
        const uint4* gl_ = (const uint4*)Wpl + (Q) * 1024;                      \
        _Pragma("unroll")                                                       \
        for (int i_ = 0; i_ < 2; ++i_) {                                        \
            gload16(gh_ + t + 512 * i_,                                         \
                    (void*)&ldsAll[(B) * 2048 + wv * 64 + 512 * i_]);           \
            gload16(gl_ + t + 512 * i_,                                         \
                    (void*)&ldsAll[(B) * 2048 + 1024 + wv * 64 + 512 * i_]);    \
        }                                                                       \
    } while (0)

#define COMPUTE_S(Q, B) do {                                                    \
        const u16* bufU_ = (const u16*)(ldsAll + (B) * 2048);                   \
        _Pragma("unroll")                                                       \
        for (int l_ = 0; l_ < 2; ++l_) {                                        \
            f32x4 acc_ = {0.f, 0.f, 0.f, 0.f};                                  \
            _Pragma("unroll")                                                   \
            for (int kt_ = 0; kt_ < 8; ++kt_) {                                 \
                const int fo_ = (l_ * 8 + kt_) * 512 + lane * 8;                \
                const short8 bh_ = *(const short8*)(bufU_ + fo_);               \
                const short8 bl_ = *(const short8*)(bufU_ + 8192 + fo_);        \
                if (kt_ < 4) {                                                  \
                    acc_ = __builtin_amdgcn_mfma_f32_16x16x32_bf16(am[kt_], bh_, acc_, 0, 0, 0); \
                    acc_ = __builtin_amdgcn_mfma_f32_16x16x32_bf16(am[kt_], bl_, acc_, 0, 0, 0); \
                } else {                                                        \
                    acc_ = __builtin_amdgcn_mfma_f32_16x16x32_bf16(ah[kt_ - 4], bh_, acc_, 0, 0, 0); \
                    acc_ = __builtin_amdgcn_mfma_f32_16x16x32_bf16(ah[kt_ - 4], bl_, acc_, 0, 0, 0); \
                    acc_ = __builtin_amdgcn_mfma_f32_16x16x32_bf16(al[kt_ - 4], bh_, acc_, 0, 0, 0); \
                }                                                               \
            }                                                                   \
            acc8[(Q) >> 1][((Q) & 1) * 2 + l_] = acc_;                          \
        }                                                                       \
    } while (0)

    STAGE_W(0, 0);
    __builtin_amdgcn_sched_barrier(0);          // keep L0 older than L1 in ledger
    STAGE_W(1, 1);
    asm volatile("s_waitcnt vmcnt(4)" ::: "memory");   // gather/A + L0 done, L1 in flight
    __builtin_amdgcn_s_barrier();
    COMPUTE_S(0, 0);
    __builtin_amdgcn_s_barrier();               // all waves done reading buf0
    STAGE_W(2, 0);
    asm volatile("s_waitcnt vmcnt(4)" ::: "memory");   // L1 done, L2 in flight
    __builtin_amdgcn_s_barrier();
    COMPUTE_S(1, 1);
    __builtin_amdgcn_s_barrier();               // all waves done reading buf1
    STAGE_W(3, 1);
    asm volatile("s_waitcnt vmcnt(4)" ::: "memory");   // L2 done, L3 in flight
    __builtin_amdgcn_s_barrier();
    COMPUTE_S(2, 0);
    asm volatile("s_waitcnt vmcnt(0)" ::: "memory");   // L3 done (had all of C2)
    __builtin_amdgcn_s_barrier();
    COMPUTE_S(3, 1);

    if (rowdot) {
        float wsum[4] = {0.f, 0.f, 0.f, 0.f};
        #pragma unroll
        for (int si = 0; si < 2; ++si) {
            #pragma unroll
            for (int nt2 = 0; nt2 < 4; ++nt2) {
                const int col = (si * 4 + nt2) * 16 + cl;
                const float bv = bias[col];
                const float wroc = Wro[col];
                #pragma unroll
                for (int r = 0; r < 4; ++r) {
                    const float v = fmaxf(acc8[si][nt2][r] + bv, 0.f);
                    wsum[r] = fmaf(v, wroc, wsum[r]);
                }
            }
        }
        #pragma unroll
        for (int r = 0; r < 4; ++r) {
            float tsum = wsum[r];
            tsum += __shfl_down(tsum, 8, 64);
            tsum += __shfl_down(tsum, 4, 64);
            tsum += __shfl_down(tsum, 2, 64);
            tsum += __shfl_down(tsum, 1, 64);
            const int row = m0 + g4 + r;
            if (cl == 0 && row < N_NODES) {
                rowdot[row] = tsum;   // plain store, row owned by this wave
            }
        }
    } else {
        #pragma unroll
        for (int si = 0; si < 2; ++si) {
            // pass 1: bias+relu+split; hi plane -> swizzled LDS, lo bits -> regs
            asm volatile("s_waitcnt lgkmcnt(0)" ::: "memory");  // prior readback done
            unsigned int lo_pack[8];
            #pragma unroll
            for (int nt2 = 0; nt2 < 4; ++nt2) {
                const int col = (si * 4 + nt2) * 16 + cl;
                const float bv = bias[col];
                #pragma unroll
                for (int r = 0; r < 4; ++r) {
                    const int rr = g4 + r;
                    const float v = fmaxf(acc8[si][nt2][r] + bv, 0.f);
                    unsigned int h16, l16;
                    split2(v, h16, l16);
                    const int boff = (rr * 128 + (nt2 * 16 + cl) * 2) ^ ((rr & 7) << 4);
                    *(u16*)(bounceB + boff) = (u16)h16;
                    if (r & 1) lo_pack[nt2 * 2 + (r >> 1)] |= l16 << 16;
                    else       lo_pack[nt2 * 2 + (r >> 1)]  = l16;
                }
            }
            asm volatile("s_waitcnt lgkmcnt(0)" ::: "memory");
            // hi readback: contiguous 16 B/lane, full 128 B row chunks to global
            #pragma unroll
            for (int j = 0; j < 2; ++j) {
                const int rr = j * 8 + (lane >> 3);
                const int blk = lane & 7;
                const uint4 vv = *(const uint4*)(bounceB + rr * 128 + ((blk ^ (rr & 7)) << 4));
                const int grow = m0 + rr;
                if (grow < N_NODES)
                    *(uint4*)(OHhi + (size_t)grow * D + si * 64 + blk * 8) = vv;
            }
            asm volatile("s_waitcnt lgkmcnt(0)" ::: "memory");
            // pass 2: lo plane through the same bounce tile
            #pragma unroll
            for (int nt2 = 0; nt2 < 4; ++nt2) {
                #pragma unroll
                for (int r = 0; r < 4; ++r) {
                    const int rr = g4 + r;
                    const unsigned int l16 = (lo_pack[nt2 * 2 + (r >> 1)] >> ((r & 1) * 16)) & 0xffffu;
                    const int boff = (rr * 128 + (nt2 * 16 + cl) * 2) ^ ((rr & 7) << 4);
                    *(u16*)(bounceB + boff) = (u16)l16;
                }
            }
            asm volatile("s_waitcnt lgkmcnt(0)" ::: "memory");
            #pragma unroll
            for (int j = 0; j < 2; ++j) {
                const int rr = j * 8 + (lane >> 3);
                const int blk = lane & 7;
                const uint4 vv = *(const uint4*)(bounceB + rr * 128 + ((blk ^ (rr & 7)) << 4));
                const int grow = m0 + rr;
                if (grow < N_NODES)
                    *(uint4*)(OHlo + (size_t)grow * D + si * 64 + blk * 8) = vv;
            }
        }
    }
#undef STAGE_W
#undef COMPUTE_S
}

// ---------------- final: per-graph sum of rowdot + sigmoid (batch sorted) ----------------
__global__ __launch_bounds__(64) void final_kernel(const float* __restrict__ rowdot,
                                                   const int* __restrict__ batch,
                                                   const float* __restrict__ bro,
                                                   float* __restrict__ out) {
    const int g = blockIdx.x;
    const int t = threadIdx.x;
    int lo = 0, hi = N_NODES;
    while (lo < hi) { int mid = (lo + hi) >> 1; if (batch[mid] < g) lo = mid + 1; else hi = mid; }
    int lo2 = lo, hi2 = N_NODES;
    while (lo2 < hi2) { int mid = (lo2 + hi2) >> 1; if (batch[mid] < g + 1) lo2 = mid + 1; else hi2 = mid; }

    float acc = 0.0f;
    for (int i = lo + t; i < lo2; i += 64) acc += rowdot[i];
    #pragma unroll
    for (int off = 32; off > 0; off >>= 1) acc += __shfl_down(acc, off, 64);
    if (t == 0) out[g] = 1.0f / (1.0f + expf(-(acc + bro[0])));
}

extern "C" void kernel_launch(void* const* d_in, const int* in_sizes, int n_in,
                              void* d_out, int out_size, void* d_ws, size_t ws_size,
                              hipStream_t stream) {
    const float* x     = (const float*)d_in[0];
    const int*   ei    = (const int*)d_in[1];
    const int*   batch = (const int*)d_in[2];
    const int*   src   = ei;
    const int*   dst   = ei + N_EDGES;
    const float* Wl[3] = {(const float*)d_in[3], (const float*)d_in[6], (const float*)d_in[9]};
    const float* Wr[3] = {(const float*)d_in[4], (const float*)d_in[7], (const float*)d_in[10]};
    const float* bs[3] = {(const float*)d_in[5], (const float*)d_in[8], (const float*)d_in[11]};
    const float* Wro   = (const float*)d_in[12];
    const float* bro   = (const float*)d_in[13];
    float* out = (float*)d_out;

    const size_t ND = (size_t)N_NODES * D;
    char* ws = (char*)d_ws;
    u16* Ahi = (u16*)ws;                           // ND u16 (ping-pong plane A)
    u16* Alo = Ahi + ND;                           // ND u16
    u16* Bhi = Alo + ND;                           // ND u16 (ping-pong plane B)
    u16* Blo = Bhi + ND;                           // ND u16
    u16* Wph = Blo + ND;                           // 3*32768 u16
    u16* Wpl = Wph + 3 * 32768;                    // 3*32768 u16
    int* deg      = (int*)(Wpl + 3 * 32768);       // N (deg+fill zeroed together)
    int* fill     = deg + N_NODES;                 // N
    float* rowdot = (float*)(fill + N_NODES);      // N
    int* excl     = (int*)(rowdot + N_NODES);      // N
    int* blocksum = excl + N_NODES;                // 128
    int* rowptr   = blocksum + 128;                // N+1
    int* csr_src  = rowptr + N_NODES + 1;          // E

    const int EB      = (N_EDGES + 255) / 256;
    const int NB      = (N_NODES + 255) / 256;
    const int NB2     = (2 * N_NODES + 255) / 256;
    const int EPB     = ((E4 + 255) / 256) * NPART;          // partitioned (fill)
    const int PREP_B  = SPLIT_B + 48;                        // fused split + wprep
    const int GEMM_B  = (N_NODES + 127) / 128;               // 782

    // ---- CSR build ----
    zero_i_kernel<<<NB2, 256, 0, stream>>>(deg, 2 * N_NODES);
    hist_kernel<<<EB, 256, 0, stream>>>(dst, deg);
    scan1_kernel<<<SCAN_NBC, SCAN_BS, 0, stream>>>(deg, excl, blocksum);
    scan3_kernel<<<NB, 256, 0, stream>>>(excl, blocksum, rowptr);
    fill_kernel<<<EPB, 256, 0, stream>>>(src, dst, rowptr, fill, csr_src);

    // ---- fused prep: split x + pack weights (into plane A) ----
    prep_kernel<<<PREP_B, 256, 0, stream>>>(x, Ahi, Alo,
                                            Wl[0], Wr[0], Wl[1], Wr[1], Wl[2], Wr[2],
                                            Wph, Wpl);

    // ---- 3 fused agg+GEMM layers, ping-pong A<->B; layer 3 -> rowdot ----
    // l=0: A -> B; l=1: B -> A; l=2: A -> rowdot
    gemm_kernel<<<GEMM_B, 512, 0, stream>>>(Ahi, Alo, rowptr, csr_src,
                                            Wph, Wpl, bs[0],
                                            Bhi, Blo, Wro, (float*)nullptr);
    gemm_kernel<<<GEMM_B, 512, 0, stream>>>(Bhi, Blo, rowptr, csr_src,
                                            Wph + 32768, Wpl + 32768, bs[1],
                                            Ahi, Alo, Wro, (float*)nullptr);
    gemm_kernel<<<GEMM_B, 512, 0, stream>>>(Ahi, Alo, rowptr, csr_src,
                                            Wph + 2 * 32768, Wpl + 2 * 32768, bs[2],
                                            Bhi, Blo, Wro, rowdot);

    // ---- per-graph sum + sigmoid ----
    final_kernel<<<N_GRAPHS, 64, 0, stream>>>(rowdot, batch, bro, out);
}

// Round 8
// 513.883 us; speedup vs baseline: 1.0688x; 1.0688x over previous
//
#include <hip/hip_runtime.h>
#include <math.h>

#define N_NODES 100000
#define N_EDGES 600000
#define N_GRAPHS 512
#define D 128
#define SCAN_BS 1024
#define SCAN_NBC ((N_NODES + SCAN_BS - 1) / SCAN_BS)   // 98
#define NPART 8
#define PART_SZ (N_NODES / NPART)                      // 12500
#define E4 (N_EDGES / 4)                               // 150000
#define SPLIT_B 12500                                  // (N*D/4)/256

typedef unsigned short u16;
typedef __attribute__((ext_vector_type(8))) short short8;
typedef __attribute__((ext_vector_type(4))) float f32x4;

__device__ __forceinline__ u16 f2bf(float f) {
    unsigned int u = __float_as_uint(f);
    u += 0x7FFFu + ((u >> 16) & 1u);
    return (u16)(u >> 16);
}
__device__ __forceinline__ float bf2f(u16 h) {
    return __uint_as_float(((unsigned int)h) << 16);
}
// fp32 -> (hi bf16 bits, lo bf16 bits) in low 16 of each
__device__ __forceinline__ void split2(float f, unsigned int& h16, unsigned int& l16) {
    unsigned int u = __float_as_uint(f);
    unsigned int hb = (u + (0x7FFFu + ((u >> 16) & 1u))) & 0xffff0000u;
    float lo = f - __uint_as_float(hb);
    unsigned int ul = __float_as_uint(lo);
    h16 = hb >> 16;
    l16 = (ul + (0x7FFFu + ((ul >> 16) & 1u))) >> 16;
}

// async global->LDS, 16 B per lane. LDS dest must be wave-uniform base + lane*16.
typedef __attribute__((address_space(1))) const unsigned int gas_u32;
typedef __attribute__((address_space(3))) unsigned int las_u32;
__device__ __forceinline__ void gload16(const void* g, void* l) {
    __builtin_amdgcn_global_load_lds((gas_u32*)g, (las_u32*)l, 16, 0, 0);
}

// ---------------- zero helper ----------------
__global__ __launch_bounds__(256) void zero_i_kernel(int* __restrict__ p, int n) {
    int i = blockIdx.x * 256 + threadIdx.x;
    if (i < n) p[i] = 0;
}

// ---------------- CSR build ----------------
// hist: plain unpartitioned (atomics execute at the device coherence point --
// R3 post-mortem). fill: KEEPS dst-range partitioning: its win is the csr_src
// SCATTER-STORE locality in the owning XCD's L2 (R2->R3).
__global__ __launch_bounds__(256) void hist_kernel(const int* __restrict__ dst,
                                                   int* __restrict__ deg) {
    int e = blockIdx.x * 256 + threadIdx.x;
    if (e < N_EDGES) atomicAdd(&deg[dst[e]], 1);
}

__global__ __launch_bounds__(1024) void scan1_kernel(const int* __restrict__ deg,
                                                     int* __restrict__ excl,
                                                     int* __restrict__ blocksum) {
    __shared__ int buf[2][SCAN_BS];
    const int t = threadIdx.x;
    const int gid = blockIdx.x * SCAN_BS + t;
    int v = (gid < N_NODES) ? deg[gid] : 0;
    buf[0][t] = v;
    __syncthreads();
    int pi = 0;
    for (int off = 1; off < SCAN_BS; off <<= 1) {
        int val = buf[pi][t];
        if (t >= off) val += buf[pi][t - off];
        buf[pi ^ 1][t] = val;
        pi ^= 1;
        __syncthreads();
    }
    int incl = buf[pi][t];
    if (gid < N_NODES) excl[gid] = incl - v;
    if (t == SCAN_BS - 1) blocksum[blockIdx.x] = incl;
}

// scan3 with the block-total prefix computed locally (merged scan2)
__global__ __launch_bounds__(256) void scan3_kernel(const int* __restrict__ excl,
                                                    const int* __restrict__ blocksum,
                                                    int* __restrict__ rowptr) {
    __shared__ int buf[2][128];
    const int t = threadIdx.x;
    if (t < 128) buf[0][t] = (t < SCAN_NBC) ? blocksum[t] : 0;
    __syncthreads();
    int pi = 0;
    for (int off = 1; off < 128; off <<= 1) {
        if (t < 128) {
            int val = buf[pi][t];
            if (t >= off) val += buf[pi][t - off];
            buf[pi ^ 1][t] = val;
        }
        pi ^= 1;
        __syncthreads();
    }
    const int i = blockIdx.x * 256 + t;
    if (i < N_NODES) {
        const int j = i / SCAN_BS;
        const int pref = (j == 0) ? 0 : buf[pi][j - 1];
        rowptr[i] = excl[i] + pref;
    }
    if (i == 0) rowptr[N_NODES] = N_EDGES;
}

__global__ __launch_bounds__(256) void fill_kernel(const int* __restrict__ src,
                                                   const int* __restrict__ dst,
                                                   const int* __restrict__ rowptr,
                                                   int* __restrict__ fill,
                                                   int* __restrict__ csr_src) {
    const int lo = (blockIdx.x & (NPART - 1)) * PART_SZ;
    const int i4 = (blockIdx.x >> 3) * 256 + threadIdx.x;
    if (i4 >= E4) return;
    const int4 d4 = ((const int4*)dst)[i4];
    const int4 s4 = ((const int4*)src)[i4];
    if ((unsigned)(d4.x - lo) < (unsigned)PART_SZ) {
        int pos = rowptr[d4.x] + atomicAdd(&fill[d4.x], 1);
        csr_src[pos] = s4.x;
    }
    if ((unsigned)(d4.y - lo) < (unsigned)PART_SZ) {
        int pos = rowptr[d4.y] + atomicAdd(&fill[d4.y], 1);
        csr_src[pos] = s4.y;
    }
    if ((unsigned)(d4.z - lo) < (unsigned)PART_SZ) {
        int pos = rowptr[d4.z] + atomicAdd(&fill[d4.z], 1);
        csr_src[pos] = s4.z;
    }
    if ((unsigned)(d4.w - lo) < (unsigned)PART_SZ) {
        int pos = rowptr[d4.w] + atomicAdd(&fill[d4.w], 1);
        csr_src[pos] = s4.w;
    }
}

// ---------------- fused prep: split x into bf16 hi/lo planes + pack W ----------------
__global__ __launch_bounds__(256) void prep_kernel(const float* __restrict__ x,
                                                   u16* __restrict__ Hhi,
                                                   u16* __restrict__ Hlo,
                                                   const float* __restrict__ Wl1, const float* __restrict__ Wr1,
                                                   const float* __restrict__ Wl2, const float* __restrict__ Wr2,
                                                   const float* __restrict__ Wl3, const float* __restrict__ Wr3,
                                                   u16* __restrict__ wph, u16* __restrict__ wpl) {
    if (blockIdx.x < SPLIT_B) {
        const int i = blockIdx.x * 256 + threadIdx.x;   // 4 elems/thread
        const float4 v = ((const float4*)x)[i];
        unsigned int h0, l0, h1, l1, h2, l2, h3, l3;
        split2(v.x, h0, l0); split2(v.y, h1, l1);
        split2(v.z, h2, l2); split2(v.w, h3, l3);
        uint2 oh, ol;
        oh.x = h0 | (h1 << 16); oh.y = h2 | (h3 << 16);
        ol.x = l0 | (l1 << 16); ol.y = l2 | (l3 << 16);
        ((uint2*)Hhi)[i] = oh;
        ((uint2*)Hlo)[i] = ol;
    } else {
        const int b = (blockIdx.x - SPLIT_B) * 4 + (threadIdx.x >> 6);  // 0..191
        const int lane = threadIdx.x & 63;
        const int layer = b >> 6;
        const int t = b & 63;
        const float* Wl = (layer == 0) ? Wl1 : (layer == 1) ? Wl2 : Wl3;
        const float* Wr = (layer == 0) ? Wr1 : (layer == 1) ? Wr2 : Wr3;
        const int nt = t >> 3, kt = t & 7;
        const int n = nt * 16 + (lane & 15);
        const int k0 = kt * 32 + (lane >> 4) * 8;
        const size_t base = (size_t)layer * 32768 + (size_t)(t * 64 + lane) * 8;
        #pragma unroll
        for (int j = 0; j < 8; ++j) {
            const int k = k0 + j;
            const float w = (k < 128) ? Wl[k * 128 + n] : Wr[(k - 128) * 128 + n];
            const u16 h = f2bf(w);
            wph[base + j] = h;
            wpl[base + j] = f2bf(w - bf2f(h));
        }
    }
}

// ---------------- FUSED agg + MFMA GEMM ----------------
// h' = relu([mean_nbr(INhi) | IN] @ [Wl;Wr] + b), OUT != IN (ping-pong), so the
// neighbor gather cannot race the epilogue writes.
// R8 gather: R6 dataflow (single ac[4][8] accumulator, constant indices ONLY)
// + depth-1 ROW prefetch into named regs (c0..c3 <- p0..p3) + depth-2 INDEX
// prefetch, pipelining the idx->row dependency across iterations.
// R7 post-mortem (549 us): forming float* pointers into a 2-bank accumulator
// array defeated SROA -> ac spilled to scratch (WRITE 50->208 MB, FETCH
// 93->163 MB, gemm 67->133 us). Rule #20: named registers, compile-time
// indexing, no address-taking in the hot loop.
// W pipeline unchanged (R1 ledger): four 32 KB stages, 2x32 KB LDS dbuf via
// global_load_lds, raw s_barrier + counted vmcnt; gather/A loads drain before
// the first counted wait (vmcnt waits oldest-first -> stricter only).
// vmcnt(4) before C0/C1/C2, vmcnt(0) before C3. LDS 80 KB -> 2 blocks/CU.
// Layer 3: rowdot[row] = sum_col relu(.)*Wro[col] (no h' write).
__global__ __launch_bounds__(512, 4) void gemm_kernel(const u16* __restrict__ INhi,
                                                      const u16* __restrict__ INlo,
                                                      const int* __restrict__ rowptr,
                                                      const int* __restrict__ csr_src,
                                                      const u16* __restrict__ Wph,
                                                      const u16* __restrict__ Wpl,
                                                      const float* __restrict__ bias,
                                                      u16* __restrict__ OHhi,
                                                      u16* __restrict__ OHlo,
                                                      const float* __restrict__ Wro,
                                                      float* rowdot) {
    __shared__ uint4 ldsAll[5120];   // 80 KB: W dbuf [0:4096) + C bounce [4096:5120)
    const int t = threadIdx.x;
    const int lane = t & 63;
    const int wv = t >> 6;
    const int m0 = blockIdx.x * 128 + wv * 16;
    const int row16 = m0 + (lane & 15);
    int rm = row16; if (rm >= N_NODES) rm = 0;
    const int ko = (lane >> 4) * 8;

    int beg = 0, deg = 0;
    if (row16 < N_NODES) {
        beg = rowptr[row16];
        deg = rowptr[row16 + 1] - beg;
    }

    // root A fragments issued FIRST: latency hides under the gather
    short8 ah[4], al[4];
    #pragma unroll
    for (int kt = 0; kt < 4; ++kt) {
        ah[kt] = *(const short8*)(INhi + (size_t)rm * D + kt * 32 + ko);
        al[kt] = *(const short8*)(INlo + (size_t)rm * D + kt * 32 + ko);
    }

    // ---- fused aggregation: depth-2 idx / depth-1 row software pipeline ----
    float ac[4][8];
    #pragma unroll
    for (int kt = 0; kt < 4; ++kt)
        #pragma unroll
        for (int j = 0; j < 8; ++j) ac[kt][j] = 0.f;

    int s_nxt = (1 < deg) ? csr_src[beg + 1] : 0;
    {
        const int s0 = (deg > 0) ? csr_src[beg] : 0;
        const size_t rb0 = (size_t)s0 * D + ko;
        uint4 c0 = *(const uint4*)(INhi + rb0);
        uint4 c1 = *(const uint4*)(INhi + rb0 + 32);
        uint4 c2 = *(const uint4*)(INhi + rb0 + 64);
        uint4 c3 = *(const uint4*)(INhi + rb0 + 96);

        for (int n = 0; __any(n < deg); ++n) {
            const int s_n2 = (n + 2 < deg) ? csr_src[beg + n + 2] : 0;  // idx 2 ahead
            uint4 p0, p1, p2, p3;
            if (n + 1 < deg) {                                           // row 1 ahead
                const size_t rbn = (size_t)s_nxt * D + ko;
                p0 = *(const uint4*)(INhi + rbn);
                p1 = *(const uint4*)(INhi + rbn + 32);
                p2 = *(const uint4*)(INhi + rbn + 64);
                p3 = *(const uint4*)(INhi + rbn + 96);
            }
            if (n < deg) {
                ac[0][0] += __uint_as_float(c0.x << 16); ac[0][1] += __uint_as_float(c0.x & 0xffff0000u);
                ac[0][2] += __uint_as_float(c0.y << 16); ac[0][3] += __uint_as_float(c0.y & 0xffff0000u);
                ac[0][4] += __uint_as_float(c0.z << 16); ac[0][5] += __uint_as_float(c0.z & 0xffff0000u);
                ac[0][6] += __uint_as_float(c0.w << 16); ac[0][7] += __uint_as_float(c0.w & 0xffff0000u);
                ac[1][0] += __uint_as_float(c1.x << 16); ac[1][1] += __uint_as_float(c1.x & 0xffff0000u);
                ac[1][2] += __uint_as_float(c1.y << 16); ac[1][3] += __uint_as_float(c1.y & 0xffff0000u);
                ac[1][4] += __uint_as_float(c1.z << 16); ac[1][5] += __uint_as_float(c1.z & 0xffff0000u);
                ac[1][6] += __uint_as_float(c1.w << 16); ac[1][7] += __uint_as_float(c1.w & 0xffff0000u);
                ac[2][0] += __uint_as_float(c2.x << 16); ac[2][1] += __uint_as_float(c2.x & 0xffff0000u);
                ac[2][2] += __uint_as_float(c2.y << 16); ac[2][3] += __uint_as_float(c2.y & 0xffff0000u);
                ac[2][4] += __uint_as_float(c2.z << 16); ac[2][5] += __uint_as_float(c2.z & 0xffff0000u);
                ac[2][6] += __uint_as_float(c2.w << 16); ac[2][7] += __uint_as_float(c2.w & 0xffff0000u);
                ac[3][0] += __uint_as_float(c3.x << 16); ac[3][1] += __uint_as_float(c3.x & 0xffff0000u);
                ac[3][2] += __uint_as_float(c3.y << 16); ac[3][3] += __uint_as_float(c3.y & 0xffff0000u);
                ac[3][4] += __uint_as_float(c3.z << 16); ac[3][5] += __uint_as_float(c3.z & 0xffff0000u);
                ac[3][6] += __uint_as_float(c3.w << 16); ac[3][7] += __uint_as_float(c3.w & 0xffff0000u);
            }
            if (n + 1 < deg) { c0 = p0; c1 = p1; c2 = p2; c3 = p3; }
            s_nxt = s_n2;
        }
    }
    const float inv = 1.0f / (float)max(deg, 1);
    short8 am[4];
    #pragma unroll
    for (int kt = 0; kt < 4; ++kt) {
        uint4 u;
        u.x = (unsigned)f2bf(ac[kt][0] * inv) | ((unsigned)f2bf(ac[kt][1] * inv) << 16);
        u.y = (unsigned)f2bf(ac[kt][2] * inv) | ((unsigned)f2bf(ac[kt][3] * inv) << 16);
        u.z = (unsigned)f2bf(ac[kt][4] * inv) | ((unsigned)f2bf(ac[kt][5] * inv) << 16);
        u.w = (unsigned)f2bf(ac[kt][6] * inv) | ((unsigned)f2bf(ac[kt][7] * inv) << 16);
        am[kt] = __builtin_bit_cast(short8, u);
    }
    __builtin_amdgcn_sched_barrier(0);   // fence gather VMEM out of the ledger

    const int cl = lane & 15;
    const int g4 = (lane >> 4) << 2;
    char* bounceB = (char*)ldsAll + 65536 + wv * 2048;   // per-wave 2 KB

    f32x4 acc8[2][4];   // [s][nt2], all indices compile-time after unroll

#define STAGE_W(Q, B) do {                                                      \
        const uint4* gh_ = (const uint4*)Wph + (Q) * 1024;                      \
        const uint4* gl_ = (const uint4*)Wpl + (Q) * 1024;                      \
        _Pragma("unroll")                                                       \
        for (int i_ = 0; i_ < 2; ++i_) {                                        \
            gload16(gh_ + t + 512 * i_,                                         \
                    (void*)&ldsAll[(B) * 2048 + wv * 64 + 512 * i_]);           \
            gload16(gl_ + t + 512 * i_,                                         \
                    (void*)&ldsAll[(B) * 2048 + 1024 + wv * 64 + 512 * i_]);    \
        }                                                                       \
    } while (0)

#define COMPUTE_S(Q, B) do {                                                    \
        const u16* bufU_ = (const u16*)(ldsAll + (B) * 2048);                   \
        _Pragma("unroll")                                                       \
        for (int l_ = 0; l_ < 2; ++l_) {                                        \
            f32x4 acc_ = {0.f, 0.f, 0.f, 0.f};                                  \
            _Pragma("unroll")                                                   \
            for (int kt_ = 0; kt_ < 8; ++kt_) {                                 \
                const int fo_ = (l_ * 8 + kt_) * 512 + lane * 8;                \
                const short8 bh_ = *(const short8*)(bufU_ + fo_);               \
                const short8 bl_ = *(const short8*)(bufU_ + 8192 + fo_);        \
                if (kt_ < 4) {                                                  \
                    acc_ = __builtin_amdgcn_mfma_f32_16x16x32_bf16(am[kt_], bh_, acc_, 0, 0, 0); \
                    acc_ = __builtin_amdgcn_mfma_f32_16x16x32_bf16(am[kt_], bl_, acc_, 0, 0, 0); \
                } else {                                                        \
                    acc_ = __builtin_amdgcn_mfma_f32_16x16x32_bf16(ah[kt_ - 4], bh_, acc_, 0, 0, 0); \
                    acc_ = __builtin_amdgcn_mfma_f32_16x16x32_bf16(ah[kt_ - 4], bl_, acc_, 0, 0, 0); \
                    acc_ = __builtin_amdgcn_mfma_f32_16x16x32_bf16(al[kt_ - 4], bh_, acc_, 0, 0, 0); \
                }                                                               \
            }                                                                   \
            acc8[(Q) >> 1][((Q) & 1) * 2 + l_] = acc_;                          \
        }                                                                       \
    } while (0)

    STAGE_W(0, 0);
    __builtin_amdgcn_sched_barrier(0);          // keep L0 older than L1 in ledger
    STAGE_W(1, 1);
    asm volatile("s_waitcnt vmcnt(4)" ::: "memory");   // gather/A + L0 done, L1 in flight
    __builtin_amdgcn_s_barrier();
    COMPUTE_S(0, 0);
    __builtin_amdgcn_s_barrier();               // all waves done reading buf0
    STAGE_W(2, 0);
    asm volatile("s_waitcnt vmcnt(4)" ::: "memory");   // L1 done, L2 in flight
    __builtin_amdgcn_s_barrier();
    COMPUTE_S(1, 1);
    __builtin_amdgcn_s_barrier();               // all waves done reading buf1
    STAGE_W(3, 1);
    asm volatile("s_waitcnt vmcnt(4)" ::: "memory");   // L2 done, L3 in flight
    __builtin_amdgcn_s_barrier();
    COMPUTE_S(2, 0);
    asm volatile("s_waitcnt vmcnt(0)" ::: "memory");   // L3 done (had all of C2)
    __builtin_amdgcn_s_barrier();
    COMPUTE_S(3, 1);

    if (rowdot) {
        float wsum[4] = {0.f, 0.f, 0.f, 0.f};
        #pragma unroll
        for (int si = 0; si < 2; ++si) {
            #pragma unroll
            for (int nt2 = 0; nt2 < 4; ++nt2) {
                const int col = (si * 4 + nt2) * 16 + cl;
                const float bv = bias[col];
                const float wroc = Wro[col];
                #pragma unroll
                for (int r = 0; r < 4; ++r) {
                    const float v = fmaxf(acc8[si][nt2][r] + bv, 0.f);
                    wsum[r] = fmaf(v, wroc, wsum[r]);
                }
            }
        }
        #pragma unroll
        for (int r = 0; r < 4; ++r) {
            float tsum = wsum[r];
            tsum += __shfl_down(tsum, 8, 64);
            tsum += __shfl_down(tsum, 4, 64);
            tsum += __shfl_down(tsum, 2, 64);
            tsum += __shfl_down(tsum, 1, 64);
            const int row = m0 + g4 + r;
            if (cl == 0 && row < N_NODES) {
                rowdot[row] = tsum;   // plain store, row owned by this wave
            }
        }
    } else {
        #pragma unroll
        for (int si = 0; si < 2; ++si) {
            // pass 1: bias+relu+split; hi plane -> swizzled LDS, lo bits -> regs
            asm volatile("s_waitcnt lgkmcnt(0)" ::: "memory");  // prior readback done
            unsigned int lo_pack[8];
            #pragma unroll
            for (int nt2 = 0; nt2 < 4; ++nt2) {
                const int col = (si * 4 + nt2) * 16 + cl;
                const float bv = bias[col];
                #pragma unroll
                for (int r = 0; r < 4; ++r) {
                    const int rr = g4 + r;
                    const float v = fmaxf(acc8[si][nt2][r] + bv, 0.f);
                    unsigned int h16, l16;
                    split2(v, h16, l16);
                    const int boff = (rr * 128 + (nt2 * 16 + cl) * 2) ^ ((rr & 7) << 4);
                    *(u16*)(bounceB + boff) = (u16)h16;
                    if (r & 1) lo_pack[nt2 * 2 + (r >> 1)] |= l16 << 16;
                    else       lo_pack[nt2 * 2 + (r >> 1)]  = l16;
                }
            }
            asm volatile("s_waitcnt lgkmcnt(0)" ::: "memory");
            // hi readback: contiguous 16 B/lane, full 128 B row chunks to global
            #pragma unroll
            for (int j = 0; j < 2; ++j) {
                const int rr = j * 8 + (lane >> 3);
                const int blk = lane & 7;
                const uint4 vv = *(const uint4*)(bounceB + rr * 128 + ((blk ^ (rr & 7)) << 4));
                const int grow = m0 + rr;
                if (grow < N_NODES)
                    *(uint4*)(OHhi + (size_t)grow * D + si * 64 + blk * 8) = vv;
            }
            asm volatile("s_waitcnt lgkmcnt(0)" ::: "memory");
            // pass 2: lo plane through the same bounce tile
            #pragma unroll
            for (int nt2 = 0; nt2 < 4; ++nt2) {
                #pragma unroll
                for (int r = 0; r < 4; ++r) {
                    const int rr = g4 + r;
                    const unsigned int l16 = (lo_pack[nt2 * 2 + (r >> 1)] >> ((r & 1) * 16)) & 0xffffu;
                    const int boff = (rr * 128 + (nt2 * 16 + cl) * 2) ^ ((rr & 7) << 4);
                    *(u16*)(bounceB + boff) = (u16)l16;
                }
            }
            asm volatile("s_waitcnt lgkmcnt(0)" ::: "memory");
            #pragma unroll
            for (int j = 0; j < 2; ++j) {
                const int rr = j * 8 + (lane >> 3);
                const int blk = lane & 7;
                const uint4 vv = *(const uint4*)(bounceB + rr * 128 + ((blk ^ (rr & 7)) << 4));
                const int grow = m0 + rr;
                if (grow < N_NODES)
                    *(uint4*)(OHlo + (size_t)grow * D + si * 64 + blk * 8) = vv;
            }
        }
    }
#undef STAGE_W
#undef COMPUTE_S
}

// ---------------- final: per-graph sum of rowdot + sigmoid (batch sorted) ----------------
__global__ __launch_bounds__(64) void final_kernel(const float* __restrict__ rowdot,
                                                   const int* __restrict__ batch,
                                                   const float* __restrict__ bro,
                                                   float* __restrict__ out) {
    const int g = blockIdx.x;
    const int t = threadIdx.x;
    int lo = 0, hi = N_NODES;
    while (lo < hi) { int mid = (lo + hi) >> 1; if (batch[mid] < g) lo = mid + 1; else hi = mid; }
    int lo2 = lo, hi2 = N_NODES;
    while (lo2 < hi2) { int mid = (lo2 + hi2) >> 1; if (batch[mid] < g + 1) lo2 = mid + 1; else hi2 = mid; }

    float acc = 0.0f;
    for (int i = lo + t; i < lo2; i += 64) acc += rowdot[i];
    #pragma unroll
    for (int off = 32; off > 0; off >>= 1) acc += __shfl_down(acc, off, 64);
    if (t == 0) out[g] = 1.0f / (1.0f + expf(-(acc + bro[0])));
}

extern "C" void kernel_launch(void* const* d_in, const int* in_sizes, int n_in,
                              void* d_out, int out_size, void* d_ws, size_t ws_size,
                              hipStream_t stream) {
    const float* x     = (const float*)d_in[0];
    const int*   ei    = (const int*)d_in[1];
    const int*   batch = (const int*)d_in[2];
    const int*   src   = ei;
    const int*   dst   = ei + N_EDGES;
    const float* Wl[3] = {(const float*)d_in[3], (const float*)d_in[6], (const float*)d_in[9]};
    const float* Wr[3] = {(const float*)d_in[4], (const float*)d_in[7], (const float*)d_in[10]};
    const float* bs[3] = {(const float*)d_in[5], (const float*)d_in[8], (const float*)d_in[11]};
    const float* Wro   = (const float*)d_in[12];
    const float* bro   = (const float*)d_in[13];
    float* out = (float*)d_out;

    const size_t ND = (size_t)N_NODES * D;
    char* ws = (char*)d_ws;
    u16* Ahi = (u16*)ws;                           // ND u16 (ping-pong plane A)
    u16* Alo = Ahi + ND;                           // ND u16
    u16* Bhi = Alo + ND;                           // ND u16 (ping-pong plane B)
    u16* Blo = Bhi + ND;                           // ND u16
    u16* Wph = Blo + ND;                           // 3*32768 u16
    u16* Wpl = Wph + 3 * 32768;                    // 3*32768 u16
    int* deg      = (int*)(Wpl + 3 * 32768);       // N (deg+fill zeroed together)
    int* fill     = deg + N_NODES;                 // N
    float* rowdot = (float*)(fill + N_NODES);      // N
    int* excl     = (int*)(rowdot + N_NODES);      // N
    int* blocksum = excl + N_NODES;                // 128
    int* rowptr   = blocksum + 128;                // N+1
    int* csr_src  = rowptr + N_NODES + 1;          // E

    const int EB      = (N_EDGES + 255) / 256;
    const int NB      = (N_NODES + 255) / 256;
    const int NB2     = (2 * N_NODES + 255) / 256;
    const int EPB     = ((E4 + 255) / 256) * NPART;          // partitioned (fill)
    const int PREP_B  = SPLIT_B + 48;                        // fused split + wprep
    const int GEMM_B  = (N_NODES + 127) / 128;               // 782

    // ---- CSR build ----
    zero_i_kernel<<<NB2, 256, 0, stream>>>(deg, 2 * N_NODES);
    hist_kernel<<<EB, 256, 0, stream>>>(dst, deg);
    scan1_kernel<<<SCAN_NBC, SCAN_BS, 0, stream>>>(deg, excl, blocksum);
    scan3_kernel<<<NB, 256, 0, stream>>>(excl, blocksum, rowptr);
    fill_kernel<<<EPB, 256, 0, stream>>>(src, dst, rowptr, fill, csr_src);

    // ---- fused prep: split x + pack weights (into plane A) ----
    prep_kernel<<<PREP_B, 256, 0, stream>>>(x, Ahi, Alo,
                                            Wl[0], Wr[0], Wl[1], Wr[1], Wl[2], Wr[2],
                                            Wph, Wpl);

    // ---- 3 fused agg+GEMM layers, ping-pong A<->B; layer 3 -> rowdot ----
    // l=0: A -> B; l=1: B -> A; l=2: A -> rowdot
    gemm_kernel<<<GEMM_B, 512, 0, stream>>>(Ahi, Alo, rowptr, csr_src,
                                            Wph, Wpl, bs[0],
                                            Bhi, Blo, Wro, (float*)nullptr);
    gemm_kernel<<<GEMM_B, 512, 0, stream>>>(Bhi, Blo, rowptr, csr_src,
                                            Wph + 32768, Wpl + 32768, bs[1],
                                            Ahi, Alo, Wro, (float*)nullptr);
    gemm_kernel<<<GEMM_B, 512, 0, stream>>>(Ahi, Alo, rowptr, csr_src,
                                            Wph + 2 * 32768, Wpl + 2 * 32768, bs[2],
                                            Bhi, Blo, Wro, rowdot);

    // ---- per-graph sum + sigmoid ----
    final_kernel<<<N_GRAPHS, 64, 0, stream>>>(rowdot, batch, bro, out);
}

// Round 9
// 363.647 us; speedup vs baseline: 1.5103x; 1.4131x over previous
//
#include <hip/hip_runtime.h>
#include <math.h>

#define N_NODES 100000
#define N_EDGES 600000
#define N_GRAPHS 512
#define D 128
#define SCAN_BS 1024
#define SCAN_NBC ((N_NODES + SCAN_BS - 1) / SCAN_BS)   // 98
#define NPART 8
#define PART_SZ (N_NODES / NPART)                      // 12500
#define E4 (N_EDGES / 4)                               // 150000
#define SPLIT_B 12500                                  // (N*D/4)/256

typedef unsigned short u16;
typedef __attribute__((ext_vector_type(8))) short short8;
typedef __attribute__((ext_vector_type(4))) float f32x4;

__device__ __forceinline__ u16 f2bf(float f) {
    unsigned int u = __float_as_uint(f);
    u += 0x7FFFu + ((u >> 16) & 1u);
    return (u16)(u >> 16);
}
__device__ __forceinline__ float bf2f(u16 h) {
    return __uint_as_float(((unsigned int)h) << 16);
}
// fp32 -> (hi bf16 bits, lo bf16 bits) in low 16 of each
__device__ __forceinline__ void split2(float f, unsigned int& h16, unsigned int& l16) {
    unsigned int u = __float_as_uint(f);
    unsigned int hb = (u + (0x7FFFu + ((u >> 16) & 1u))) & 0xffff0000u;
    float lo = f - __uint_as_float(hb);
    unsigned int ul = __float_as_uint(lo);
    h16 = hb >> 16;
    l16 = (ul + (0x7FFFu + ((ul >> 16) & 1u))) >> 16;
}

// async global->LDS, 16 B per lane. LDS dest must be wave-uniform base + lane*16.
typedef __attribute__((address_space(1))) const unsigned int gas_u32;
typedef __attribute__((address_space(3))) unsigned int las_u32;
__device__ __forceinline__ void gload16(const void* g, void* l) {
    __builtin_amdgcn_global_load_lds((gas_u32*)g, (las_u32*)l, 16, 0, 0);
}

// ---------------- zero helper ----------------
__global__ __launch_bounds__(256) void zero_i_kernel(int* __restrict__ p, int n) {
    int i = blockIdx.x * 256 + threadIdx.x;
    if (i < n) p[i] = 0;
}

// ---------------- CSR build ----------------
// hist: plain unpartitioned (atomics execute at the device coherence point --
// R3 post-mortem). fill: KEEPS dst-range partitioning: its win is the csr_src
// SCATTER-STORE locality in the owning XCD's L2 (R2->R3).
__global__ __launch_bounds__(256) void hist_kernel(const int* __restrict__ dst,
                                                   int* __restrict__ deg) {
    int e = blockIdx.x * 256 + threadIdx.x;
    if (e < N_EDGES) atomicAdd(&deg[dst[e]], 1);
}

__global__ __launch_bounds__(1024) void scan1_kernel(const int* __restrict__ deg,
                                                     int* __restrict__ excl,
                                                     int* __restrict__ blocksum) {
    __shared__ int buf[2][SCAN_BS];
    const int t = threadIdx.x;
    const int gid = blockIdx.x * SCAN_BS + t;
    int v = (gid < N_NODES) ? deg[gid] : 0;
    buf[0][t] = v;
    __syncthreads();
    int pi = 0;
    for (int off = 1; off < SCAN_BS; off <<= 1) {
        int val = buf[pi][t];
        if (t >= off) val += buf[pi][t - off];
        buf[pi ^ 1][t] = val;
        pi ^= 1;
        __syncthreads();
    }
    int incl = buf[pi][t];
    if (gid < N_NODES) excl[gid] = incl - v;
    if (t == SCAN_BS - 1) blocksum[blockIdx.x] = incl;
}

// scan3 with the block-total prefix computed locally (merged scan2)
__global__ __launch_bounds__(256) void scan3_kernel(const int* __restrict__ excl,
                                                    const int* __restrict__ blocksum,
                                                    int* __restrict__ rowptr) {
    __shared__ int buf[2][128];
    const int t = threadIdx.x;
    if (t < 128) buf[0][t] = (t < SCAN_NBC) ? blocksum[t] : 0;
    __syncthreads();
    int pi = 0;
    for (int off = 1; off < 128; off <<= 1) {
        if (t < 128) {
            int val = buf[pi][t];
            if (t >= off) val += buf[pi][t - off];
            buf[pi ^ 1][t] = val;
        }
        pi ^= 1;
        __syncthreads();
    }
    const int i = blockIdx.x * 256 + t;
    if (i < N_NODES) {
        const int j = i / SCAN_BS;
        const int pref = (j == 0) ? 0 : buf[pi][j - 1];
        rowptr[i] = excl[i] + pref;
    }
    if (i == 0) rowptr[N_NODES] = N_EDGES;
}

__global__ __launch_bounds__(256) void fill_kernel(const int* __restrict__ src,
                                                   const int* __restrict__ dst,
                                                   const int* __restrict__ rowptr,
                                                   int* __restrict__ fill,
                                                   int* __restrict__ csr_src) {
    const int lo = (blockIdx.x & (NPART - 1)) * PART_SZ;
    const int i4 = (blockIdx.x >> 3) * 256 + threadIdx.x;
    if (i4 >= E4) return;
    const int4 d4 = ((const int4*)dst)[i4];
    const int4 s4 = ((const int4*)src)[i4];
    if ((unsigned)(d4.x - lo) < (unsigned)PART_SZ) {
        int pos = rowptr[d4.x] + atomicAdd(&fill[d4.x], 1);
        csr_src[pos] = s4.x;
    }
    if ((unsigned)(d4.y - lo) < (unsigned)PART_SZ) {
        int pos = rowptr[d4.y] + atomicAdd(&fill[d4.y], 1);
        csr_src[pos] = s4.y;
    }
    if ((unsigned)(d4.z - lo) < (unsigned)PART_SZ) {
        int pos = rowptr[d4.z] + atomicAdd(&fill[d4.z], 1);
        csr_src[pos] = s4.z;
    }
    if ((unsigned)(d4.w - lo) < (unsigned)PART_SZ) {
        int pos = rowptr[d4.w] + atomicAdd(&fill[d4.w], 1);
        csr_src[pos] = s4.w;
    }
}

// ---------------- fused prep: split x into bf16 hi/lo planes + pack W ----------------
__global__ __launch_bounds__(256) void prep_kernel(const float* __restrict__ x,
                                                   u16* __restrict__ Hhi,
                                                   u16* __restrict__ Hlo,
                                                   const float* __restrict__ Wl1, const float* __restrict__ Wr1,
                                                   const float* __restrict__ Wl2, const float* __restrict__ Wr2,
                                                   const float* __restrict__ Wl3, const float* __restrict__ Wr3,
                                                   u16* __restrict__ wph, u16* __restrict__ wpl) {
    if (blockIdx.x < SPLIT_B) {
        const int i = blockIdx.x * 256 + threadIdx.x;   // 4 elems/thread
        const float4 v = ((const float4*)x)[i];
        unsigned int h0, l0, h1, l1, h2, l2, h3, l3;
        split2(v.x, h0, l0); split2(v.y, h1, l1);
        split2(v.z, h2, l2); split2(v.w, h3, l3);
        uint2 oh, ol;
        oh.x = h0 | (h1 << 16); oh.y = h2 | (h3 << 16);
        ol.x = l0 | (l1 << 16); ol.y = l2 | (l3 << 16);
        ((uint2*)Hhi)[i] = oh;
        ((uint2*)Hlo)[i] = ol;
    } else {
        const int b = (blockIdx.x - SPLIT_B) * 4 + (threadIdx.x >> 6);  // 0..191
        const int lane = threadIdx.x & 63;
        const int layer = b >> 6;
        const int t = b & 63;
        const float* Wl = (layer == 0) ? Wl1 : (layer == 1) ? Wl2 : Wl3;
        const float* Wr = (layer == 0) ? Wr1 : (layer == 1) ? Wr2 : Wr3;
        const int nt = t >> 3, kt = t & 7;
        const int n = nt * 16 + (lane & 15);
        const int k0 = kt * 32 + (lane >> 4) * 8;
        const size_t base = (size_t)layer * 32768 + (size_t)(t * 64 + lane) * 8;
        #pragma unroll
        for (int j = 0; j < 8; ++j) {
            const int k = k0 + j;
            const float w = (k < 128) ? Wl[k * 128 + n] : Wr[(k - 128) * 128 + n];
            const u16 h = f2bf(w);
            wph[base + j] = h;
            wpl[base + j] = f2bf(w - bf2f(h));
        }
    }
}

// ---------------- FUSED agg + MFMA GEMM ----------------
// h' = relu([mean_nbr(INhi) | IN] @ [Wl;Wr] + b), OUT != IN (ping-pong), so the
// neighbor gather cannot race the epilogue writes.
// R9: exact R6 gather dataflow (VGPR 52, no scratch -- R7/R8's deeper gather
// pipelines both spilled: the 128-VGPR cap of (512,4) has no headroom; that
// axis is closed). ONE change vs R6: STAGE_W(0/1) are ISSUED BEFORE the
// gather, so the 64 KB W fetch flies under ~25 us of gather latency instead of
// starting after it. vmcnt is in-order, so the gather's own data-dependency
// waits (newer than L0/L1) drain the W stages for free; first wait becomes
// vmcnt(0) (same cost), and C1 needs NO wait (buf1 fully populated before C0).
// L2/L3 keep the counted ledger: vmcnt(4) before C2, vmcnt(0) before C3.
// Identical math order -> bit-identical output vs R6.
// LDS 80 KB -> 2 blocks/CU. Layer 3: rowdot[row] = sum_col relu(.)*Wro[col].
__global__ __launch_bounds__(512, 4) void gemm_kernel(const u16* __restrict__ INhi,
                                                      const u16* __restrict__ INlo,
                                                      const int* __restrict__ rowptr,
                                                      const int* __restrict__ csr_src,
                                                      const u16* __restrict__ Wph,
                                                      const u16* __restrict__ Wpl,
                                                      const float* __restrict__ bias,
                                                      u16* __restrict__ OHhi,
                                                      u16* __restrict__ OHlo,
                                                      const float* __restrict__ Wro,
                                                      float* rowdot) {
    __shared__ uint4 ldsAll[5120];   // 80 KB: W dbuf [0:4096) + C bounce [4096:5120)
    const int t = threadIdx.x;
    const int lane = t & 63;
    const int wv = t >> 6;
    const int m0 = blockIdx.x * 128 + wv * 16;
    const int row16 = m0 + (lane & 15);
    int rm = row16; if (rm >= N_NODES) rm = 0;
    const int ko = (lane >> 4) * 8;

    int beg = 0, deg = 0;
    if (row16 < N_NODES) {
        beg = rowptr[row16];
        deg = rowptr[row16 + 1] - beg;
    }

#define STAGE_W(Q, B) do {                                                      \
        const uint4* gh_ = (const uint4*)Wph + (Q) * 1024;                      \
        const uint4* gl_ = (const uint4*)Wpl + (Q) * 1024;                      \
        _Pragma("unroll")                                                       \
        for (int i_ = 0; i_ < 2; ++i_) {                                        \
            gload16(gh_ + t + 512 * i_,                                         \
                    (void*)&ldsAll[(B) * 2048 + wv * 64 + 512 * i_]);           \
            gload16(gl_ + t + 512 * i_,                                         \
                    (void*)&ldsAll[(B) * 2048 + 1024 + wv * 64 + 512 * i_]);    \
        }                                                                       \
    } while (0)

    // W stages 0 and 1 issued FIRST: their HBM fetch overlaps the gather.
    STAGE_W(0, 0);
    __builtin_amdgcn_sched_barrier(0);
    STAGE_W(1, 1);
    __builtin_amdgcn_sched_barrier(0);

    // root A fragments: latency hides under the gather
    short8 ah[4], al[4];
    #pragma unroll
    for (int kt = 0; kt < 4; ++kt) {
        ah[kt] = *(const short8*)(INhi + (size_t)rm * D + kt * 32 + ko);
        al[kt] = *(const short8*)(INlo + (size_t)rm * D + kt * 32 + ko);
    }

    // ---- fused aggregation (R6 form): mean of neighbor rows, 32 cols/lane ----
    float ac[4][8];
    #pragma unroll
    for (int kt = 0; kt < 4; ++kt) {
        #pragma unroll
        for (int j = 0; j < 8; ++j) ac[kt][j] = 0.f;
    }
    int s_cur = (deg > 0) ? csr_src[beg] : 0;
    for (int n = 0; __any(n < deg); ++n) {
        const bool act = n < deg;
        const int s_nxt = (n + 1 < deg) ? csr_src[beg + n + 1] : 0;
        if (act) {
            const size_t rb = (size_t)s_cur * D + ko;
            #pragma unroll
            for (int kt = 0; kt < 4; ++kt) {
                const uint4 v = *(const uint4*)(INhi + rb + kt * 32);
                ac[kt][0] += __uint_as_float(v.x << 16);
                ac[kt][1] += __uint_as_float(v.x & 0xffff0000u);
                ac[kt][2] += __uint_as_float(v.y << 16);
                ac[kt][3] += __uint_as_float(v.y & 0xffff0000u);
                ac[kt][4] += __uint_as_float(v.z << 16);
                ac[kt][5] += __uint_as_float(v.z & 0xffff0000u);
                ac[kt][6] += __uint_as_float(v.w << 16);
                ac[kt][7] += __uint_as_float(v.w & 0xffff0000u);
            }
        }
        s_cur = s_nxt;
    }
    const float inv = 1.0f / (float)max(deg, 1);
    short8 am[4];
    #pragma unroll
    for (int kt = 0; kt < 4; ++kt) {
        uint4 u;
        u.x = (unsigned)f2bf(ac[kt][0] * inv) | ((unsigned)f2bf(ac[kt][1] * inv) << 16);
        u.y = (unsigned)f2bf(ac[kt][2] * inv) | ((unsigned)f2bf(ac[kt][3] * inv) << 16);
        u.z = (unsigned)f2bf(ac[kt][4] * inv) | ((unsigned)f2bf(ac[kt][5] * inv) << 16);
        u.w = (unsigned)f2bf(ac[kt][6] * inv) | ((unsigned)f2bf(ac[kt][7] * inv) << 16);
        am[kt] = __builtin_bit_cast(short8, u);
    }
    __builtin_amdgcn_sched_barrier(0);

    const int cl = lane & 15;
    const int g4 = (lane >> 4) << 2;
    char* bounceB = (char*)ldsAll + 65536 + wv * 2048;   // per-wave 2 KB

    f32x4 acc8[2][4];   // [s][nt2], all indices compile-time after unroll

#define COMPUTE_S(Q, B) do {                                                    \
        const u16* bufU_ = (const u16*)(ldsAll + (B) * 2048);                   \
        _Pragma("unroll")                                                       \
        for (int l_ = 0; l_ < 2; ++l_) {                                        \
            f32x4 acc_ = {0.f, 0.f, 0.f, 0.f};                                  \
            _Pragma("unroll")                                                   \
            for (int kt_ = 0; kt_ < 8; ++kt_) {                                 \
                const int fo_ = (l_ * 8 + kt_) * 512 + lane * 8;                \
                const short8 bh_ = *(const short8*)(bufU_ + fo_);               \
                const short8 bl_ = *(const short8*)(bufU_ + 8192 + fo_);        \
                if (kt_ < 4) {                                                  \
                    acc_ = __builtin_amdgcn_mfma_f32_16x16x32_bf16(am[kt_], bh_, acc_, 0, 0, 0); \
                    acc_ = __builtin_amdgcn_mfma_f32_16x16x32_bf16(am[kt_], bl_, acc_, 0, 0, 0); \
                } else {                                                        \
                    acc_ = __builtin_amdgcn_mfma_f32_16x16x32_bf16(ah[kt_ - 4], bh_, acc_, 0, 0, 0); \
                    acc_ = __builtin_amdgcn_mfma_f32_16x16x32_bf16(ah[kt_ - 4], bl_, acc_, 0, 0, 0); \
                    acc_ = __builtin_amdgcn_mfma_f32_16x16x32_bf16(al[kt_ - 4], bh_, acc_, 0, 0, 0); \
                }                                                               \
            }                                                                   \
            acc8[(Q) >> 1][((Q) & 1) * 2 + l_] = acc_;                          \
        }                                                                       \
    } while (0)

    asm volatile("s_waitcnt vmcnt(0)" ::: "memory");   // gather + L0 + L1 all done
    __builtin_amdgcn_s_barrier();                      // buf0+buf1 fully populated
    COMPUTE_S(0, 0);
    __builtin_amdgcn_s_barrier();               // all waves done reading buf0
    STAGE_W(2, 0);
    COMPUTE_S(1, 1);                            // no wait: buf1 warm since C0
    __builtin_amdgcn_s_barrier();               // all waves done reading buf1
    STAGE_W(3, 1);
    asm volatile("s_waitcnt vmcnt(4)" ::: "memory");   // own L2 done, L3 in flight
    __builtin_amdgcn_s_barrier();               // all waves' L2 done
    COMPUTE_S(2, 0);
    asm volatile("s_waitcnt vmcnt(0)" ::: "memory");   // L3 done (had all of C2)
    __builtin_amdgcn_s_barrier();
    COMPUTE_S(3, 1);

    if (rowdot) {
        float wsum[4] = {0.f, 0.f, 0.f, 0.f};
        #pragma unroll
        for (int si = 0; si < 2; ++si) {
            #pragma unroll
            for (int nt2 = 0; nt2 < 4; ++nt2) {
                const int col = (si * 4 + nt2) * 16 + cl;
                const float bv = bias[col];
                const float wroc = Wro[col];
                #pragma unroll
                for (int r = 0; r < 4; ++r) {
                    const float v = fmaxf(acc8[si][nt2][r] + bv, 0.f);
                    wsum[r] = fmaf(v, wroc, wsum[r]);
                }
            }
        }
        #pragma unroll
        for (int r = 0; r < 4; ++r) {
            float tsum = wsum[r];
            tsum += __shfl_down(tsum, 8, 64);
            tsum += __shfl_down(tsum, 4, 64);
            tsum += __shfl_down(tsum, 2, 64);
            tsum += __shfl_down(tsum, 1, 64);
            const int row = m0 + g4 + r;
            if (cl == 0 && row < N_NODES) {
                rowdot[row] = tsum;   // plain store, row owned by this wave
            }
        }
    } else {
        #pragma unroll
        for (int si = 0; si < 2; ++si) {
            // pass 1: bias+relu+split; hi plane -> swizzled LDS, lo bits -> regs
            asm volatile("s_waitcnt lgkmcnt(0)" ::: "memory");  // prior readback done
            unsigned int lo_pack[8];
            #pragma unroll
            for (int nt2 = 0; nt2 < 4; ++nt2) {
                const int col = (si * 4 + nt2) * 16 + cl;
                const float bv = bias[col];
                #pragma unroll
                for (int r = 0; r < 4; ++r) {
                    const int rr = g4 + r;
                    const float v = fmaxf(acc8[si][nt2][r] + bv, 0.f);
                    unsigned int h16, l16;
                    split2(v, h16, l16);
                    const int boff = (rr * 128 + (nt2 * 16 + cl) * 2) ^ ((rr & 7) << 4);
                    *(u16*)(bounceB + boff) = (u16)h16;
                    if (r & 1) lo_pack[nt2 * 2 + (r >> 1)] |= l16 << 16;
                    else       lo_pack[nt2 * 2 + (r >> 1)]  = l16;
                }
            }
            asm volatile("s_waitcnt lgkmcnt(0)" ::: "memory");
            // hi readback: contiguous 16 B/lane, full 128 B row chunks to global
            #pragma unroll
            for (int j = 0; j < 2; ++j) {
                const int rr = j * 8 + (lane >> 3);
                const int blk = lane & 7;
                const uint4 vv = *(const uint4*)(bounceB + rr * 128 + ((blk ^ (rr & 7)) << 4));
                const int grow = m0 + rr;
                if (grow < N_NODES)
                    *(uint4*)(OHhi + (size_t)grow * D + si * 64 + blk * 8) = vv;
            }
            asm volatile("s_waitcnt lgkmcnt(0)" ::: "memory");
            // pass 2: lo plane through the same bounce tile
            #pragma unroll
            for (int nt2 = 0; nt2 < 4; ++nt2) {
                #pragma unroll
                for (int r = 0; r < 4; ++r) {
                    const int rr = g4 + r;
                    const unsigned int l16 = (lo_pack[nt2 * 2 + (r >> 1)] >> ((r & 1) * 16)) & 0xffffu;
                    const int boff = (rr * 128 + (nt2 * 16 + cl) * 2) ^ ((rr & 7) << 4);
                    *(u16*)(bounceB + boff) = (u16)l16;
                }
            }
            asm volatile("s_waitcnt lgkmcnt(0)" ::: "memory");
            #pragma unroll
            for (int j = 0; j < 2; ++j) {
                const int rr = j * 8 + (lane >> 3);
                const int blk = lane & 7;
                const uint4 vv = *(const uint4*)(bounceB + rr * 128 + ((blk ^ (rr & 7)) << 4));
                const int grow = m0 + rr;
                if (grow < N_NODES)
                    *(uint4*)(OHlo + (size_t)grow * D + si * 64 + blk * 8) = vv;
            }
        }
    }
#undef STAGE_W
#undef COMPUTE_S
}

// ---------------- final: per-graph sum of rowdot + sigmoid (batch sorted) ----------------
__global__ __launch_bounds__(64) void final_kernel(const float* __restrict__ rowdot,
                                                   const int* __restrict__ batch,
                                                   const float* __restrict__ bro,
                                                   float* __restrict__ out) {
    const int g = blockIdx.x;
    const int t = threadIdx.x;
    int lo = 0, hi = N_NODES;
    while (lo < hi) { int mid = (lo + hi) >> 1; if (batch[mid] < g) lo = mid + 1; else hi = mid; }
    int lo2 = lo, hi2 = N_NODES;
    while (lo2 < hi2) { int mid = (lo2 + hi2) >> 1; if (batch[mid] < g + 1) lo2 = mid + 1; else hi2 = mid; }

    float acc = 0.0f;
    for (int i = lo + t; i < lo2; i += 64) acc += rowdot[i];
    #pragma unroll
    for (int off = 32; off > 0; off >>= 1) acc += __shfl_down(acc, off, 64);
    if (t == 0) out[g] = 1.0f / (1.0f + expf(-(acc + bro[0])));
}

extern "C" void kernel_launch(void* const* d_in, const int* in_sizes, int n_in,
                              void* d_out, int out_size, void* d_ws, size_t ws_size,
                              hipStream_t stream) {
    const float* x     = (const float*)d_in[0];
    const int*   ei    = (const int*)d_in[1];
    const int*   batch = (const int*)d_in[2];
    const int*   src   = ei;
    const int*   dst   = ei + N_EDGES;
    const float* Wl[3] = {(const float*)d_in[3], (const float*)d_in[6], (const float*)d_in[9]};
    const float* Wr[3] = {(const float*)d_in[4], (const float*)d_in[7], (const float*)d_in[10]};
    const float* bs[3] = {(const float*)d_in[5], (const float*)d_in[8], (const float*)d_in[11]};
    const float* Wro   = (const float*)d_in[12];
    const float* bro   = (const float*)d_in[13];
    float* out = (float*)d_out;

    const size_t ND = (size_t)N_NODES * D;
    char* ws = (char*)d_ws;
    u16* Ahi = (u16*)ws;                           // ND u16 (ping-pong plane A)
    u16* Alo = Ahi + ND;                           // ND u16
    u16* Bhi = Alo + ND;                           // ND u16 (ping-pong plane B)
    u16* Blo = Bhi + ND;                           // ND u16
    u16* Wph = Blo + ND;                           // 3*32768 u16
    u16* Wpl = Wph + 3 * 32768;                    // 3*32768 u16
    int* deg      = (int*)(Wpl + 3 * 32768);       // N (deg+fill zeroed together)
    int* fill     = deg + N_NODES;                 // N
    float* rowdot = (float*)(fill + N_NODES);      // N
    int* excl     = (int*)(rowdot + N_NODES);      // N
    int* blocksum = excl + N_NODES;                // 128
    int* rowptr   = blocksum + 128;                // N+1
    int* csr_src  = rowptr + N_NODES + 1;          // E

    const int EB      = (N_EDGES + 255) / 256;
    const int NB      = (N_NODES + 255) / 256;
    const int NB2     = (2 * N_NODES + 255) / 256;
    const int EPB     = ((E4 + 255) / 256) * NPART;          // partitioned (fill)
    const int PREP_B  = SPLIT_B + 48;                        // fused split + wprep
    const int GEMM_B  = (N_NODES + 127) / 128;               // 782

    // ---- CSR build ----
    zero_i_kernel<<<NB2, 256, 0, stream>>>(deg, 2 * N_NODES);
    hist_kernel<<<EB, 256, 0, stream>>>(dst, deg);
    scan1_kernel<<<SCAN_NBC, SCAN_BS, 0, stream>>>(deg, excl, blocksum);
    scan3_kernel<<<NB, 256, 0, stream>>>(excl, blocksum, rowptr);
    fill_kernel<<<EPB, 256, 0, stream>>>(src, dst, rowptr, fill, csr_src);

    // ---- fused prep: split x + pack weights (into plane A) ----
    prep_kernel<<<PREP_B, 256, 0, stream>>>(x, Ahi, Alo,
                                            Wl[0], Wr[0], Wl[1], Wr[1], Wl[2], Wr[2],
                                            Wph, Wpl);

    // ---- 3 fused agg+GEMM layers, ping-pong A<->B; layer 3 -> rowdot ----
    // l=0: A -> B; l=1: B -> A; l=2: A -> rowdot
    gemm_kernel<<<GEMM_B, 512, 0, stream>>>(Ahi, Alo, rowptr, csr_src,
                                            Wph, Wpl, bs[0],
                                            Bhi, Blo, Wro, (float*)nullptr);
    gemm_kernel<<<GEMM_B, 512, 0, stream>>>(Bhi, Blo, rowptr, csr_src,
                                            Wph + 32768, Wpl + 32768, bs[1],
                                            Ahi, Alo, Wro, (float*)nullptr);
    gemm_kernel<<<GEMM_B, 512, 0, stream>>>(Ahi, Alo, rowptr, csr_src,
                                            Wph + 2 * 32768, Wpl + 2 * 32768, bs[2],
                                            Bhi, Blo, Wro, rowdot);

    // ---- per-graph sum + sigmoid ----
    final_kernel<<<N_GRAPHS, 64, 0, stream>>>(rowdot, batch, bro, out);
}

// Round 10
// 362.220 us; speedup vs baseline: 1.5163x; 1.0039x over previous
//
#include <hip/hip_runtime.h>
#include <math.h>

#define N_NODES 100000
#define N_EDGES 600000
#define N_GRAPHS 512
#define D 128
#define SCAN_BS 1024
#define SCAN_NBC ((N_NODES + SCAN_BS - 1) / SCAN_BS)   // 98
#define NPART 8
#define PART_SZ (N_NODES / NPART)                      // 12500
#define E4 (N_EDGES / 4)                               // 150000
#define SPLIT_B 12500                                  // (N*D/4)/256

typedef unsigned short u16;
typedef __attribute__((ext_vector_type(8))) short short8;
typedef __attribute__((ext_vector_type(4))) float f32x4;

__device__ __forceinline__ u16 f2bf(float f) {
    unsigned int u = __float_as_uint(f);
    u += 0x7FFFu + ((u >> 16) & 1u);
    return (u16)(u >> 16);
}
__device__ __forceinline__ float bf2f(u16 h) {
    return __uint_as_float(((unsigned int)h) << 16);
}
// fp32 -> (hi bf16 bits, lo bf16 bits) in low 16 of each
__device__ __forceinline__ void split2(float f, unsigned int& h16, unsigned int& l16) {
    unsigned int u = __float_as_uint(f);
    unsigned int hb = (u + (0x7FFFu + ((u >> 16) & 1u))) & 0xffff0000u;
    float lo = f - __uint_as_float(hb);
    unsigned int ul = __float_as_uint(lo);
    h16 = hb >> 16;
    l16 = (ul + (0x7FFFu + ((ul >> 16) & 1u))) >> 16;
}

// async global->LDS, 16 B per lane. LDS dest must be wave-uniform base + lane*16.
typedef __attribute__((address_space(1))) const unsigned int gas_u32;
typedef __attribute__((address_space(3))) unsigned int las_u32;
__device__ __forceinline__ void gload16(const void* g, void* l) {
    __builtin_amdgcn_global_load_lds((gas_u32*)g, (las_u32*)l, 16, 0, 0);
}

// ---------------- zero helper ----------------
__global__ __launch_bounds__(256) void zero_i_kernel(int* __restrict__ p, int n) {
    int i = blockIdx.x * 256 + threadIdx.x;
    if (i < n) p[i] = 0;
}

// ---------------- CSR build ----------------
// hist: plain unpartitioned (atomics execute at the device coherence point --
// R3 post-mortem). fill: KEEPS dst-range partitioning: its win is the csr_src
// SCATTER-STORE locality in the owning XCD's L2 (R2->R3).
__global__ __launch_bounds__(256) void hist_kernel(const int* __restrict__ dst,
                                                   int* __restrict__ deg) {
    int e = blockIdx.x * 256 + threadIdx.x;
    if (e < N_EDGES) atomicAdd(&deg[dst[e]], 1);
}

__global__ __launch_bounds__(1024) void scan1_kernel(const int* __restrict__ deg,
                                                     int* __restrict__ excl,
                                                     int* __restrict__ blocksum) {
    __shared__ int buf[2][SCAN_BS];
    const int t = threadIdx.x;
    const int gid = blockIdx.x * SCAN_BS + t;
    int v = (gid < N_NODES) ? deg[gid] : 0;
    buf[0][t] = v;
    __syncthreads();
    int pi = 0;
    for (int off = 1; off < SCAN_BS; off <<= 1) {
        int val = buf[pi][t];
        if (t >= off) val += buf[pi][t - off];
        buf[pi ^ 1][t] = val;
        pi ^= 1;
        __syncthreads();
    }
    int incl = buf[pi][t];
    if (gid < N_NODES) excl[gid] = incl - v;
    if (t == SCAN_BS - 1) blocksum[blockIdx.x] = incl;
}

// scan3 with the block-total prefix computed locally (merged scan2)
__global__ __launch_bounds__(256) void scan3_kernel(const int* __restrict__ excl,
                                                    const int* __restrict__ blocksum,
                                                    int* __restrict__ rowptr) {
    __shared__ int buf[2][128];
    const int t = threadIdx.x;
    if (t < 128) buf[0][t] = (t < SCAN_NBC) ? blocksum[t] : 0;
    __syncthreads();
    int pi = 0;
    for (int off = 1; off < 128; off <<= 1) {
        if (t < 128) {
            int val = buf[pi][t];
            if (t >= off) val += buf[pi][t - off];
            buf[pi ^ 1][t] = val;
        }
        pi ^= 1;
        __syncthreads();
    }
    const int i = blockIdx.x * 256 + t;
    if (i < N_NODES) {
        const int j = i / SCAN_BS;
        const int pref = (j == 0) ? 0 : buf[pi][j - 1];
        rowptr[i] = excl[i] + pref;
    }
    if (i == 0) rowptr[N_NODES] = N_EDGES;
}

__global__ __launch_bounds__(256) void fill_kernel(const int* __restrict__ src,
                                                   const int* __restrict__ dst,
                                                   const int* __restrict__ rowptr,
                                                   int* __restrict__ fill,
                                                   int* __restrict__ csr_src) {
    const int lo = (blockIdx.x & (NPART - 1)) * PART_SZ;
    const int i4 = (blockIdx.x >> 3) * 256 + threadIdx.x;
    if (i4 >= E4) return;
    const int4 d4 = ((const int4*)dst)[i4];
    const int4 s4 = ((const int4*)src)[i4];
    if ((unsigned)(d4.x - lo) < (unsigned)PART_SZ) {
        int pos = rowptr[d4.x] + atomicAdd(&fill[d4.x], 1);
        csr_src[pos] = s4.x;
    }
    if ((unsigned)(d4.y - lo) < (unsigned)PART_SZ) {
        int pos = rowptr[d4.y] + atomicAdd(&fill[d4.y], 1);
        csr_src[pos] = s4.y;
    }
    if ((unsigned)(d4.z - lo) < (unsigned)PART_SZ) {
        int pos = rowptr[d4.z] + atomicAdd(&fill[d4.z], 1);
        csr_src[pos] = s4.z;
    }
    if ((unsigned)(d4.w - lo) < (unsigned)PART_SZ) {
        int pos = rowptr[d4.w] + atomicAdd(&fill[d4.w], 1);
        csr_src[pos] = s4.w;
    }
}

// ---------------- fused prep: split x into bf16 hi/lo planes + pack W ----------------
__global__ __launch_bounds__(256) void prep_kernel(const float* __restrict__ x,
                                                   u16* __restrict__ Hhi,
                                                   u16* __restrict__ Hlo,
                                                   const float* __restrict__ Wl1, const float* __restrict__ Wr1,
                                                   const float* __restrict__ Wl2, const float* __restrict__ Wr2,
                                                   const float* __restrict__ Wl3, const float* __restrict__ Wr3,
                                                   u16* __restrict__ wph, u16* __restrict__ wpl) {
    if (blockIdx.x < SPLIT_B) {
        const int i = blockIdx.x * 256 + threadIdx.x;   // 4 elems/thread
        const float4 v = ((const float4*)x)[i];
        unsigned int h0, l0, h1, l1, h2, l2, h3, l3;
        split2(v.x, h0, l0); split2(v.y, h1, l1);
        split2(v.z, h2, l2); split2(v.w, h3, l3);
        uint2 oh, ol;
        oh.x = h0 | (h1 << 16); oh.y = h2 | (h3 << 16);
        ol.x = l0 | (l1 << 16); ol.y = l2 | (l3 << 16);
        ((uint2*)Hhi)[i] = oh;
        ((uint2*)Hlo)[i] = ol;
    } else {
        const int b = (blockIdx.x - SPLIT_B) * 4 + (threadIdx.x >> 6);  // 0..191
        const int lane = threadIdx.x & 63;
        const int layer = b >> 6;
        const int t = b & 63;
        const float* Wl = (layer == 0) ? Wl1 : (layer == 1) ? Wl2 : Wl3;
        const float* Wr = (layer == 0) ? Wr1 : (layer == 1) ? Wr2 : Wr3;
        const int nt = t >> 3, kt = t & 7;
        const int n = nt * 16 + (lane & 15);
        const int k0 = kt * 32 + (lane >> 4) * 8;
        const size_t base = (size_t)layer * 32768 + (size_t)(t * 64 + lane) * 8;
        #pragma unroll
        for (int j = 0; j < 8; ++j) {
            const int k = k0 + j;
            const float w = (k < 128) ? Wl[k * 128 + n] : Wr[(k - 128) * 128 + n];
            const u16 h = f2bf(w);
            wph[base + j] = h;
            wpl[base + j] = f2bf(w - bf2f(h));
        }
    }
}

// ---------------- FUSED agg + MFMA GEMM ----------------
// h' = relu([mean_nbr(INhi) | IN] @ [Wl;Wr] + b), OUT != IN (ping-pong).
// R10: LDS 80 KB -> 32 KB to raise co-residency. R9 showed VGPR=64 (allows
// 32 waves/CU) but 80 KB LDS bound occupancy at 2 blocks/CU; during a block's
// ~26 us gather phase the CU idles. At 32 KB the measured 64-VGPR allocation
// gives 4 blocks/CU = 32 waves: gather latency hidden by 2x waves, W-pipeline
// barrier gaps filled by other blocks' phases.
// Changes: (1) W staged in EIGHT 16 KB stages (one col-tile each) through a
// 2x16 KB dbuf -- same issue-before-compute + counted-vmcnt pattern; ledger
// per stage = 2 gloads/thread: vmcnt(2) before C2..C6 (next stage in flight),
// vmcnt(0) before C0 (drains gather+root+L0+L1) and before C7. (2) epilogue
// bounce OVERLAYS bufA: last bufA reader is C6, fenced by the pre-C7
// vmcnt(0)+barrier; bounce slices are per-wave private.
// Race audit: bufA written L0/2/4/6, read C0/2/4/6; bufB written L1/3/5/7,
// read C1/3/5/7 -- each write issued after the trailing barrier of that
// buffer's previous reader; each read waits its stage (counted vmcnt+barrier).
// Identical math order -> bit-identical output vs R9.
// Layer 3: rowdot[row] = sum_col relu(.)*Wro[col] (no h' write).
__global__ __launch_bounds__(512, 4) void gemm_kernel(const u16* __restrict__ INhi,
                                                      const u16* __restrict__ INlo,
                                                      const int* __restrict__ rowptr,
                                                      const int* __restrict__ csr_src,
                                                      const u16* __restrict__ Wph,
                                                      const u16* __restrict__ Wpl,
                                                      const float* __restrict__ bias,
                                                      u16* __restrict__ OHhi,
                                                      u16* __restrict__ OHlo,
                                                      const float* __restrict__ Wro,
                                                      float* rowdot) {
    __shared__ uint4 ldsAll[2048];   // 32 KB: W dbuf A=[0:1024) B=[1024:2048); bounce overlays A post-C6
    const int t = threadIdx.x;
    const int lane = t & 63;
    const int wv = t >> 6;
    const int m0 = blockIdx.x * 128 + wv * 16;
    const int row16 = m0 + (lane & 15);
    int rm = row16; if (rm >= N_NODES) rm = 0;
    const int ko = (lane >> 4) * 8;

    int beg = 0, deg = 0;
    if (row16 < N_NODES) {
        beg = rowptr[row16];
        deg = rowptr[row16 + 1] - beg;
    }

    // stage Q = col-tile Q (hi 8 KB + lo 8 KB) into buffer B. 2 gloads/thread.
    // dest: wave-uniform base + lane*16 (linear); global uint4 idx = Q*512 + t.
#define STAGE_W(Q, B) do {                                                      \
        const uint4* gh_ = (const uint4*)Wph + (Q) * 512;                       \
        const uint4* gl_ = (const uint4*)Wpl + (Q) * 512;                       \
        gload16(gh_ + t, (void*)&ldsAll[(B) * 1024 + wv * 64]);                 \
        gload16(gl_ + t, (void*)&ldsAll[(B) * 1024 + 512 + wv * 64]);           \
    } while (0)

    // W stages 0 and 1 issued FIRST: their HBM fetch overlaps the gather.
    STAGE_W(0, 0);
    __builtin_amdgcn_sched_barrier(0);
    STAGE_W(1, 1);
    __builtin_amdgcn_sched_barrier(0);

    // root A fragments: latency hides under the gather
    short8 ah[4], al[4];
    #pragma unroll
    for (int kt = 0; kt < 4; ++kt) {
        ah[kt] = *(const short8*)(INhi + (size_t)rm * D + kt * 32 + ko);
        al[kt] = *(const short8*)(INlo + (size_t)rm * D + kt * 32 + ko);
    }

    // ---- fused aggregation (R6 form): mean of neighbor rows, 32 cols/lane ----
    float ac[4][8];
    #pragma unroll
    for (int kt = 0; kt < 4; ++kt) {
        #pragma unroll
        for (int j = 0; j < 8; ++j) ac[kt][j] = 0.f;
    }
    int s_cur = (deg > 0) ? csr_src[beg] : 0;
    for (int n = 0; __any(n < deg); ++n) {
        const bool act = n < deg;
        const int s_nxt = (n + 1 < deg) ? csr_src[beg + n + 1] : 0;
        if (act) {
            const size_t rb = (size_t)s_cur * D + ko;
            #pragma unroll
            for (int kt = 0; kt < 4; ++kt) {
                const uint4 v = *(const uint4*)(INhi + rb + kt * 32);
                ac[kt][0] += __uint_as_float(v.x << 16);
                ac[kt][1] += __uint_as_float(v.x & 0xffff0000u);
                ac[kt][2] += __uint_as_float(v.y << 16);
                ac[kt][3] += __uint_as_float(v.y & 0xffff0000u);
                ac[kt][4] += __uint_as_float(v.z << 16);
                ac[kt][5] += __uint_as_float(v.z & 0xffff0000u);
                ac[kt][6] += __uint_as_float(v.w << 16);
                ac[kt][7] += __uint_as_float(v.w & 0xffff0000u);
            }
        }
        s_cur = s_nxt;
    }
    const float inv = 1.0f / (float)max(deg, 1);
    short8 am[4];
    #pragma unroll
    for (int kt = 0; kt < 4; ++kt) {
        uint4 u;
        u.x = (unsigned)f2bf(ac[kt][0] * inv) | ((unsigned)f2bf(ac[kt][1] * inv) << 16);
        u.y = (unsigned)f2bf(ac[kt][2] * inv) | ((unsigned)f2bf(ac[kt][3] * inv) << 16);
        u.z = (unsigned)f2bf(ac[kt][4] * inv) | ((unsigned)f2bf(ac[kt][5] * inv) << 16);
        u.w = (unsigned)f2bf(ac[kt][6] * inv) | ((unsigned)f2bf(ac[kt][7] * inv) << 16);
        am[kt] = __builtin_bit_cast(short8, u);
    }
    __builtin_amdgcn_sched_barrier(0);

    const int cl = lane & 15;
    const int g4 = (lane >> 4) << 2;

    f32x4 acc8[2][4];   // [si][nt2], col-tile Q -> acc8[Q>>2][Q&3]

    // compute col-tile Q from buffer B: 8 kt x 5-MFMA hi/lo pattern
#define COMPUTE_S(Q, B) do {                                                    \
        const u16* bufU_ = (const u16*)(ldsAll + (B) * 1024);                   \
        f32x4 acc_ = {0.f, 0.f, 0.f, 0.f};                                      \
        _Pragma("unroll")                                                       \
        for (int kt_ = 0; kt_ < 8; ++kt_) {                                     \
            const int fo_ = kt_ * 512 + lane * 8;                               \
            const short8 bh_ = *(const short8*)(bufU_ + fo_);                   \
            const short8 bl_ = *(const short8*)(bufU_ + 4096 + fo_);            \
            if (kt_ < 4) {                                                      \
                acc_ = __builtin_amdgcn_mfma_f32_16x16x32_bf16(am[kt_], bh_, acc_, 0, 0, 0); \
                acc_ = __builtin_amdgcn_mfma_f32_16x16x32_bf16(am[kt_], bl_, acc_, 0, 0, 0); \
            } else {                                                            \
                acc_ = __builtin_amdgcn_mfma_f32_16x16x32_bf16(ah[kt_ - 4], bh_, acc_, 0, 0, 0); \
                acc_ = __builtin_amdgcn_mfma_f32_16x16x32_bf16(ah[kt_ - 4], bl_, acc_, 0, 0, 0); \
                acc_ = __builtin_amdgcn_mfma_f32_16x16x32_bf16(al[kt_ - 4], bh_, acc_, 0, 0, 0); \
            }                                                                   \
        }                                                                       \
        acc8[(Q) >> 2][(Q) & 3] = acc_;                                         \
    } while (0)

    asm volatile("s_waitcnt vmcnt(0)" ::: "memory");   // gather + root + L0 + L1 done
    __builtin_amdgcn_s_barrier();                      // buf0+buf1 fully populated
    COMPUTE_S(0, 0);
    __builtin_amdgcn_s_barrier();               // all waves done reading bufA (C0)
    STAGE_W(2, 0);
    __builtin_amdgcn_sched_barrier(0);
    COMPUTE_S(1, 1);                            // no wait: bufB warm since pre-C0 drain
    __builtin_amdgcn_s_barrier();               // all waves done reading bufB (C1)
    STAGE_W(3, 1);
    asm volatile("s_waitcnt vmcnt(2)" ::: "memory");   // L2 done, L3 in flight
    __builtin_amdgcn_s_barrier();
    COMPUTE_S(2, 0);
    __builtin_amdgcn_s_barrier();
    STAGE_W(4, 0);
    asm volatile("s_waitcnt vmcnt(2)" ::: "memory");   // L3 done, L4 in flight
    __builtin_amdgcn_s_barrier();
    COMPUTE_S(3, 1);
    __builtin_amdgcn_s_barrier();
    STAGE_W(5, 1);
    asm volatile("s_waitcnt vmcnt(2)" ::: "memory");   // L4 done, L5 in flight
    __builtin_amdgcn_s_barrier();
    COMPUTE_S(4, 0);
    __builtin_amdgcn_s_barrier();
    STAGE_W(6, 0);
    asm volatile("s_waitcnt vmcnt(2)" ::: "memory");   // L5 done, L6 in flight
    __builtin_amdgcn_s_barrier();
    COMPUTE_S(5, 1);
    __builtin_amdgcn_s_barrier();
    STAGE_W(7, 1);
    asm volatile("s_waitcnt vmcnt(2)" ::: "memory");   // L6 done, L7 in flight
    __builtin_amdgcn_s_barrier();
    COMPUTE_S(6, 0);
    asm volatile("s_waitcnt vmcnt(0)" ::: "memory");   // L7 done (had all of C6)
    __builtin_amdgcn_s_barrier();               // all waves past C6 -> bufA free
    COMPUTE_S(7, 1);

    char* bounceB = (char*)ldsAll + wv * 2048;  // per-wave 2 KB, overlays bufA

    if (rowdot) {
        float wsum[4] = {0.f, 0.f, 0.f, 0.f};
        #pragma unroll
        for (int si = 0; si < 2; ++si) {
            #pragma unroll
            for (int nt2 = 0; nt2 < 4; ++nt2) {
                const int col = (si * 4 + nt2) * 16 + cl;
                const float bv = bias[col];
                const float wroc = Wro[col];
                #pragma unroll
                for (int r = 0; r < 4; ++r) {
                    const float v = fmaxf(acc8[si][nt2][r] + bv, 0.f);
                    wsum[r] = fmaf(v, wroc, wsum[r]);
                }
            }
        }
        #pragma unroll
        for (int r = 0; r < 4; ++r) {
            float tsum = wsum[r];
            tsum += __shfl_down(tsum, 8, 64);
            tsum += __shfl_down(tsum, 4, 64);
            tsum += __shfl_down(tsum, 2, 64);
            tsum += __shfl_down(tsum, 1, 64);
            const int row = m0 + g4 + r;
            if (cl == 0 && row < N_NODES) {
                rowdot[row] = tsum;   // plain store, row owned by this wave
            }
        }
    } else {
        #pragma unroll
        for (int si = 0; si < 2; ++si) {
            // pass 1: bias+relu+split; hi plane -> swizzled LDS, lo bits -> regs
            asm volatile("s_waitcnt lgkmcnt(0)" ::: "memory");  // prior readback done
            unsigned int lo_pack[8];
            #pragma unroll
            for (int nt2 = 0; nt2 < 4; ++nt2) {
                const int col = (si * 4 + nt2) * 16 + cl;
                const float bv = bias[col];
                #pragma unroll
                for (int r = 0; r < 4; ++r) {
                    const int rr = g4 + r;
                    const float v = fmaxf(acc8[si][nt2][r] + bv, 0.f);
                    unsigned int h16, l16;
                    split2(v, h16, l16);
                    const int boff = (rr * 128 + (nt2 * 16 + cl) * 2) ^ ((rr & 7) << 4);
                    *(u16*)(bounceB + boff) = (u16)h16;
                    if (r & 1) lo_pack[nt2 * 2 + (r >> 1)] |= l16 << 16;
                    else       lo_pack[nt2 * 2 + (r >> 1)]  = l16;
                }
            }
            asm volatile("s_waitcnt lgkmcnt(0)" ::: "memory");
            // hi readback: contiguous 16 B/lane, full 128 B row chunks to global
            #pragma unroll
            for (int j = 0; j < 2; ++j) {
                const int rr = j * 8 + (lane >> 3);
                const int blk = lane & 7;
                const uint4 vv = *(const uint4*)(bounceB + rr * 128 + ((blk ^ (rr & 7)) << 4));
                const int grow = m0 + rr;
                if (grow < N_NODES)
                    *(uint4*)(OHhi + (size_t)grow * D + si * 64 + blk * 8) = vv;
            }
            asm volatile("s_waitcnt lgkmcnt(0)" ::: "memory");
            // pass 2: lo plane through the same bounce tile
            #pragma unroll
            for (int nt2 = 0; nt2 < 4; ++nt2) {
                #pragma unroll
                for (int r = 0; r < 4; ++r) {
                    const int rr = g4 + r;
                    const unsigned int l16 = (lo_pack[nt2 * 2 + (r >> 1)] >> ((r & 1) * 16)) & 0xffffu;
                    const int boff = (rr * 128 + (nt2 * 16 + cl) * 2) ^ ((rr & 7) << 4);
                    *(u16*)(bounceB + boff) = (u16)l16;
                }
            }
            asm volatile("s_waitcnt lgkmcnt(0)" ::: "memory");
            #pragma unroll
            for (int j = 0; j < 2; ++j) {
                const int rr = j * 8 + (lane >> 3);
                const int blk = lane & 7;
                const uint4 vv = *(const uint4*)(bounceB + rr * 128 + ((blk ^ (rr & 7)) << 4));
                const int grow = m0 + rr;
                if (grow < N_NODES)
                    *(uint4*)(OHlo + (size_t)grow * D + si * 64 + blk * 8) = vv;
            }
        }
    }
#undef STAGE_W
#undef COMPUTE_S
}

// ---------------- final: per-graph sum of rowdot + sigmoid (batch sorted) ----------------
__global__ __launch_bounds__(64) void final_kernel(const float* __restrict__ rowdot,
                                                   const int* __restrict__ batch,
                                                   const float* __restrict__ bro,
                                                   float* __restrict__ out) {
    const int g = blockIdx.x;
    const int t = threadIdx.x;
    int lo = 0, hi = N_NODES;
    while (lo < hi) { int mid = (lo + hi) >> 1; if (batch[mid] < g) lo = mid + 1; else hi = mid; }
    int lo2 = lo, hi2 = N_NODES;
    while (lo2 < hi2) { int mid = (lo2 + hi2) >> 1; if (batch[mid] < g + 1) lo2 = mid + 1; else hi2 = mid; }

    float acc = 0.0f;
    for (int i = lo + t; i < lo2; i += 64) acc += rowdot[i];
    #pragma unroll
    for (int off = 32; off > 0; off >>= 1) acc += __shfl_down(acc, off, 64);
    if (t == 0) out[g] = 1.0f / (1.0f + expf(-(acc + bro[0])));
}

extern "C" void kernel_launch(void* const* d_in, const int* in_sizes, int n_in,
                              void* d_out, int out_size, void* d_ws, size_t ws_size,
                              hipStream_t stream) {
    const float* x     = (const float*)d_in[0];
    const int*   ei    = (const int*)d_in[1];
    const int*   batch = (const int*)d_in[2];
    const int*   src   = ei;
    const int*   dst   = ei + N_EDGES;
    const float* Wl[3] = {(const float*)d_in[3], (const float*)d_in[6], (const float*)d_in[9]};
    const float* Wr[3] = {(const float*)d_in[4], (const float*)d_in[7], (const float*)d_in[10]};
    const float* bs[3] = {(const float*)d_in[5], (const float*)d_in[8], (const float*)d_in[11]};
    const float* Wro   = (const float*)d_in[12];
    const float* bro   = (const float*)d_in[13];
    float* out = (float*)d_out;

    const size_t ND = (size_t)N_NODES * D;
    char* ws = (char*)d_ws;
    u16* Ahi = (u16*)ws;                           // ND u16 (ping-pong plane A)
    u16* Alo = Ahi + ND;                           // ND u16
    u16* Bhi = Alo + ND;                           // ND u16 (ping-pong plane B)
    u16* Blo = Bhi + ND;                           // ND u16
    u16* Wph = Blo + ND;                           // 3*32768 u16
    u16* Wpl = Wph + 3 * 32768;                    // 3*32768 u16
    int* deg      = (int*)(Wpl + 3 * 32768);       // N (deg+fill zeroed together)
    int* fill     = deg + N_NODES;                 // N
    float* rowdot = (float*)(fill + N_NODES);      // N
    int* excl     = (int*)(rowdot + N_NODES);      // N
    int* blocksum = excl + N_NODES;                // 128
    int* rowptr   = blocksum + 128;                // N+1
    int* csr_src  = rowptr + N_NODES + 1;          // E

    const int EB      = (N_EDGES + 255) / 256;
    const int NB      = (N_NODES + 255) / 256;
    const int NB2     = (2 * N_NODES + 255) / 256;
    const int EPB     = ((E4 + 255) / 256) * NPART;          // partitioned (fill)
    const int PREP_B  = SPLIT_B + 48;                        // fused split + wprep
    const int GEMM_B  = (N_NODES + 127) / 128;               // 782

    // ---- CSR build ----
    zero_i_kernel<<<NB2, 256, 0, stream>>>(deg, 2 * N_NODES);
    hist_kernel<<<EB, 256, 0, stream>>>(dst, deg);
    scan1_kernel<<<SCAN_NBC, SCAN_BS, 0, stream>>>(deg, excl, blocksum);
    scan3_kernel<<<NB, 256, 0, stream>>>(excl, blocksum, rowptr);
    fill_kernel<<<EPB, 256, 0, stream>>>(src, dst, rowptr, fill, csr_src);

    // ---- fused prep: split x + pack weights (into plane A) ----
    prep_kernel<<<PREP_B, 256, 0, stream>>>(x, Ahi, Alo,
                                            Wl[0], Wr[0], Wl[1], Wr[1], Wl[2], Wr[2],
                                            Wph, Wpl);

    // ---- 3 fused agg+GEMM layers, ping-pong A<->B; layer 3 -> rowdot ----
    // l=0: A -> B; l=1: B -> A; l=2: A -> rowdot
    gemm_kernel<<<GEMM_B, 512, 0, stream>>>(Ahi, Alo, rowptr, csr_src,
                                            Wph, Wpl, bs[0],
                                            Bhi, Blo, Wro, (float*)nullptr);
    gemm_kernel<<<GEMM_B, 512, 0, stream>>>(Bhi, Blo, rowptr, csr_src,
                                            Wph + 32768, Wpl + 32768, bs[1],
                                            Ahi, Alo, Wro, (float*)nullptr);
    gemm_kernel<<<GEMM_B, 512, 0, stream>>>(Ahi, Alo, rowptr, csr_src,
                                            Wph + 2 * 32768, Wpl + 2 * 32768, bs[2],
                                            Bhi, Blo, Wro, rowdot);

    // ---- per-graph sum + sigmoid ----
    final_kernel<<<N_GRAPHS, 64, 0, stream>>>(rowdot, batch, bro, out);
}